// Round 1
// baseline (1999.444 us; speedup 1.0000x reference)
//
#include <hip/hip_runtime.h>

#define N_ROWS 65536
#define N_COLS 256
#define NCLASS 10
#define SPLITS 16
#define CHUNK (N_ROWS / SPLITS)   // 4096
#define NTILES 36                 // upper-tri 32x32 tiles of 8x8 grid

// ---------------- histogram of labels ----------------
__global__ void hist_kernel(const int* __restrict__ Y, int* __restrict__ counts) {
    __shared__ int h[NCLASS];
    if (threadIdx.x < NCLASS) h[threadIdx.x] = 0;
    __syncthreads();
    int idx = blockIdx.x * blockDim.x + threadIdx.x;
    int stride = gridDim.x * blockDim.x;
    for (int i = idx; i < N_ROWS; i += stride) {
        int y = Y[i];
        if (y >= 0 && y < NCLASS) atomicAdd(&h[y], 1);
    }
    __syncthreads();
    if (threadIdx.x < NCLASS) atomicAdd(&counts[threadIdx.x], h[threadIdx.x]);
}

// ---------------- per-class covariance accumulation ----------------
// grid: (NTILES, SPLITS), block: 256 threads.
// Each block owns one 32x32 output tile (pi<=qi) and a 4096-row slice.
// Each thread owns a 2x2 micro-tile per class: acc[10][4].
__global__ __launch_bounds__(256) void cov_kernel(const float* __restrict__ X,
                                                  const int* __restrict__ Y,
                                                  float* __restrict__ cov) {
    __shared__ float sA[32][36];   // +4 pad: keeps float4 alignment, spreads banks
    __shared__ float sB[32][36];
    __shared__ int   sLab[32];

    // tile id -> (pi, qi) with pi <= qi
    int t = blockIdx.x;
    int pi = 0;
    while (t >= 8 - pi) { t -= 8 - pi; ++pi; }
    int qi = pi + t;

    int tid = threadIdx.x;
    int ty = tid >> 4;    // 0..15 (p dim)
    int tx = tid & 15;    // 0..15 (q dim)

    float acc[NCLASS][4];
    #pragma unroll
    for (int c = 0; c < NCLASS; ++c) {
        #pragma unroll
        for (int v = 0; v < 4; ++v) acc[c][v] = 0.f;
    }

    int lr = tid >> 3;        // 0..31 staging row
    int lc = (tid & 7) * 4;   // 0,4,...,28 staging col (float4)

    int row0 = blockIdx.y * CHUNK;
    for (int base = 0; base < CHUNK; base += 32) {
        int r0 = row0 + base;
        const float* gp = X + (size_t)(r0 + lr) * N_COLS;
        float4 va = *(const float4*)(gp + pi * 32 + lc);
        float4 vb = *(const float4*)(gp + qi * 32 + lc);
        __syncthreads();                       // prev-iter readers done
        *(float4*)&sA[lr][lc] = va;
        *(float4*)&sB[lr][lc] = vb;
        if (tid < 32) sLab[tid] = Y[r0 + tid];
        __syncthreads();

        #pragma unroll 4
        for (int r = 0; r < 32; ++r) {
            int k = __builtin_amdgcn_readfirstlane(sLab[r]);  // block-uniform label
            float2 a = *(const float2*)&sA[r][ty * 2];
            float2 b = *(const float2*)&sB[r][tx * 2];
            float p0 = a.x * b.x, p1 = a.x * b.y, p2 = a.y * b.x, p3 = a.y * b.y;
            switch (k) {
                #define CASE(c) case c: acc[c][0]+=p0; acc[c][1]+=p1; acc[c][2]+=p2; acc[c][3]+=p3; break;
                CASE(0) CASE(1) CASE(2) CASE(3) CASE(4)
                CASE(5) CASE(6) CASE(7) CASE(8) CASE(9)
                #undef CASE
                default: break;
            }
        }
    }

    // merge split partials (upper-block storage only; LDL mirrors on read)
    int p0r = pi * 32 + ty * 2;
    int q0c = qi * 32 + tx * 2;
    #pragma unroll
    for (int c = 0; c < NCLASS; ++c) {
        float* cb = cov + (size_t)c * (N_COLS * N_COLS);
        atomicAdd(&cb[(size_t)(p0r    ) * N_COLS + q0c    ], acc[c][0]);
        atomicAdd(&cb[(size_t)(p0r    ) * N_COLS + q0c + 1], acc[c][1]);
        atomicAdd(&cb[(size_t)(p0r + 1) * N_COLS + q0c    ], acc[c][2]);
        atomicAdd(&cb[(size_t)(p0r + 1) * N_COLS + q0c + 1], acc[c][3]);
    }
}

// ---------------- LDL^T logdet, one block per matrix ----------------
// b in 0..9: M = I + (p/(trPi_b*EPS)) * cov[b];  b==10: M = I + (p/(m*EPS)) * gram
// Matrix rows in registers: thread (i = t>>2, q = t&3) owns row i cols [64q, 64q+64).
// Pivot row broadcast via 1 KB LDS. logdet = sum log(pivot_j). SPD => pivots >= 1.
__global__ __launch_bounds__(1024) void ldl_kernel(const float* __restrict__ cov,
                                                   const int* __restrict__ counts,
                                                   float* __restrict__ logdets) {
    int b = blockIdx.x;   // 0..10
    int t = threadIdx.x;
    int i = t >> 2;       // row 0..255
    int q = t & 3;
    int c0 = q * 64;

    float scal;
    if (b < 10) scal = (float)N_COLS / (((float)counts[b] + 1e-8f) * 0.01f);
    else        scal = (float)N_COLS / ((float)N_ROWS * 0.01f);

    float r[64];
    #pragma unroll
    for (int v = 0; v < 64; ++v) {
        int c = c0 + v;
        int a0 = i, b0 = c;
        if ((i >> 5) > (c >> 5)) { a0 = c; b0 = i; }   // cov stores upper 32-blocks
        size_t off = (size_t)a0 * N_COLS + b0;
        float s;
        if (b < 10) {
            s = cov[(size_t)b * (N_COLS * N_COLS) + off];
        } else {
            s = 0.f;
            #pragma unroll
            for (int k = 0; k < NCLASS; ++k)
                s += cov[(size_t)k * (N_COLS * N_COLS) + off];
        }
        r[v] = scal * s + ((c == i) ? 1.f : 0.f);
    }

    __shared__ float row[256];
    float logsum = 0.f;
    for (int j = 0; j < N_COLS; ++j) {
        if (i == j) {   // publish pivot row; zero dead cols so no inner predication
            #pragma unroll
            for (int v = 0; v < 64; ++v) row[c0 + v] = (c0 + v >= j) ? r[v] : 0.f;
        }
        __syncthreads();
        float d = row[j];
        logsum += __logf(d);
        if (i > j) {
            float s = row[i] / d;
            #pragma unroll
            for (int v = 0; v < 64; v += 4) {
                float4 rv = *(const float4*)&row[c0 + v];
                r[v]     -= s * rv.x;
                r[v + 1] -= s * rv.y;
                r[v + 2] -= s * rv.z;
                r[v + 3] -= s * rv.w;
            }
        }
        __syncthreads();
    }
    if (t == 0) logdets[b] = logsum;
}

// ---------------- finalize ----------------
__global__ void finalize_kernel(const float* __restrict__ logdets,
                                const int* __restrict__ counts,
                                float* __restrict__ out) {
    if (threadIdx.x == 0 && blockIdx.x == 0) {
        float discrimn = 0.5f * logdets[10];       // GAM1 == 1 => empi == theo
        float compress = 0.f;
        for (int k = 0; k < NCLASS; ++k) {
            float tr = (float)counts[k] + 1e-8f;
            compress += logdets[k] * tr;
        }
        compress = compress / (float)N_ROWS * 0.5f;
        out[0] = -discrimn + compress;             // GAM2 == 1
        out[1] = discrimn;
        out[2] = compress;
        out[3] = discrimn;
        out[4] = compress;
    }
}

extern "C" void kernel_launch(void* const* d_in, const int* in_sizes, int n_in,
                              void* d_out, int out_size, void* d_ws, size_t ws_size,
                              hipStream_t stream) {
    const float* X = (const float*)d_in[0];
    const int*   Y = (const int*)d_in[1];
    float* out = (float*)d_out;

    char* ws = (char*)d_ws;
    const size_t cov_bytes = (size_t)NCLASS * N_COLS * N_COLS * sizeof(float); // 2.62 MB
    float* cov     = (float*)ws;
    int*   counts  = (int*)(ws + cov_bytes);
    float* logdets = (float*)(ws + cov_bytes + 16 * sizeof(int));

    hipMemsetAsync(ws, 0, cov_bytes + 16 * sizeof(int), stream);
    hipLaunchKernelGGL(hist_kernel, dim3(64), dim3(256), 0, stream, Y, counts);
    hipLaunchKernelGGL(cov_kernel, dim3(NTILES, SPLITS), dim3(256), 0, stream, X, Y, cov);
    hipLaunchKernelGGL(ldl_kernel, dim3(11), dim3(1024), 0, stream, cov, counts, logdets);
    hipLaunchKernelGGL(finalize_kernel, dim3(1), dim3(64), 0, stream, logdets, counts, out);
}

// Round 3
// 740.047 us; speedup vs baseline: 2.7018x; 2.7018x over previous
//
#include <hip/hip_runtime.h>

#define N_ROWS 65536
#define N_COLS 256
#define NCLASS 10
#define XP 66176            // Xst col pitch: 65536 + 10*64 pad
#define SPL 16              // K-splits per (class,tile)

typedef __attribute__((ext_vector_type(8))) short bf16x8;
typedef __attribute__((ext_vector_type(4))) float f32x4;

// meta layout (ints): [0..10] off_pad, [16..26] offsets (unpadded), [32..41] counts

static __device__ __forceinline__ unsigned short f2bf(float f) {
    unsigned int u = __float_as_uint(f);
    unsigned int r = (u + 0x7FFFu + ((u >> 16) & 1u)) >> 16;   // RTN-even
    return (unsigned short)r;
}

// ---------------- Phase A: per-block class histogram ----------------
__global__ __launch_bounds__(256) void blkhist_kernel(const int* __restrict__ Y,
                                                      int* __restrict__ blk_cnt) {
    __shared__ int h[NCLASS];
    int b = blockIdx.x, t = threadIdx.x;
    if (t < NCLASS) h[t] = 0;
    __syncthreads();
    atomicAdd(&h[Y[b * 256 + t]], 1);
    __syncthreads();
    if (t < NCLASS) blk_cnt[b * NCLASS + t] = h[t];
}

// ---------------- Phase B: scan -> meta + per-block bases ----------------
__global__ __launch_bounds__(256) void scan_kernel(const int* __restrict__ blk_cnt,
                                                   int* __restrict__ meta,
                                                   int* __restrict__ blk_base) {
    __shared__ int sc[256 * NCLASS];
    __shared__ int tots[16];
    __shared__ int soff[16];
    int t = threadIdx.x;
    for (int j = t; j < 256 * NCLASS; j += 256) sc[j] = blk_cnt[j];
    __syncthreads();
    if (t < NCLASS) {
        int s = 0;
        for (int b = 0; b < 256; ++b) s += sc[b * NCLASS + t];
        tots[t] = s;
    }
    __syncthreads();
    if (t == 0) {
        int off = 0, offp = 0;
        for (int c = 0; c < NCLASS; ++c) {
            soff[c] = off;
            meta[16 + c] = off;
            meta[c] = offp;
            meta[32 + c] = tots[c];
            off += tots[c];
            offp += (tots[c] + 63) & ~63;
        }
        meta[16 + NCLASS] = off;
        meta[NCLASS] = offp;
    }
    __syncthreads();
    if (t < NCLASS) {
        int run = soff[t];
        for (int b = 0; b < 256; ++b) {
            blk_base[b * NCLASS + t] = run;
            run += sc[b * NCLASS + t];
        }
    }
}

// ---------------- Phase C: build sorted order ----------------
__global__ __launch_bounds__(256) void order_kernel(const int* __restrict__ Y,
                                                    const int* __restrict__ blk_base,
                                                    int* __restrict__ order) {
    __shared__ int lcur[NCLASS];
    int b = blockIdx.x, t = threadIdx.x;
    if (t < NCLASS) lcur[t] = 0;
    __syncthreads();
    int i = b * 256 + t;
    int y = Y[i];
    int pos = blk_base[b * NCLASS + y] + atomicAdd(&lcur[y], 1);
    order[pos] = i;
}

// ---------------- Phase D: gather + fp32->bf16 + transpose ----------------
// Xst[feature 0..255][pos 0..XP): class c occupies pos [off_pad[c], off_pad[c+1]),
// padded tail positions are zero columns (contribute 0 to cov).
__global__ __launch_bounds__(256) void gather_kernel(const float* __restrict__ X,
                                                     const int* __restrict__ order,
                                                     const int* __restrict__ meta,
                                                     unsigned short* __restrict__ Xst) {
    __shared__ unsigned short sT[256 * 65];
    int p0 = blockIdx.x * 64;
    if (p0 >= meta[NCLASS]) return;          // beyond total padded count
    int cls = 0;
    while (p0 >= meta[cls + 1]) ++cls;       // 64-tiles never straddle classes
    int lp0 = p0 - meta[cls];
    int cnt = meta[32 + cls];
    int obase = meta[16 + cls];

    int t = threadIdx.x;
    int p = t >> 2;                 // 0..63 local pos
    int cseg = (t & 3) * 64;        // feature segment
    int lp = lp0 + p;
    int row = (lp < cnt) ? order[obase + lp] : -1;
    const float* xr = X + (size_t)(row < 0 ? 0 : row) * N_COLS;
    #pragma unroll
    for (int k = 0; k < 16; ++k) {
        int col = cseg + k * 4;
        float4 v;
        if (row >= 0) v = *(const float4*)(xr + col);
        else          v = make_float4(0.f, 0.f, 0.f, 0.f);
        sT[(col + 0) * 65 + p] = f2bf(v.x);
        sT[(col + 1) * 65 + p] = f2bf(v.y);
        sT[(col + 2) * 65 + p] = f2bf(v.z);
        sT[(col + 3) * 65 + p] = f2bf(v.w);
    }
    __syncthreads();
    int l = t & 63, w = t >> 6;
    #pragma unroll 8
    for (int k = 0; k < 64; ++k) {
        int col = w * 64 + k;
        Xst[(size_t)col * XP + p0 + l] = sT[col * 65 + l];
    }
}

// ---------------- cov via bf16 MFMA syrk ----------------
// grid (3 tiles, 10 classes, SPL splits), 256 threads = 4 waves.
// Tile 0:(0,0) 1:(0,1) 2:(1,1) of 128x128; wave w -> 64x64 sub-tile; 4x4 mfma 16x16x32.
__global__ __launch_bounds__(256) void cov_mfma(const unsigned short* __restrict__ Xst,
                                                const int* __restrict__ meta,
                                                float* __restrict__ cov) {
    __shared__ unsigned short sA[128][72];   // pitch 72 elems (144B, 16B-aligned)
    __shared__ unsigned short sB[128][72];
    int cls = blockIdx.y;
    int tile = blockIdx.x;
    int ti = (tile == 2) ? 1 : 0;
    int tj = (tile == 0) ? 0 : 1;
    int kb = meta[cls];
    int len = meta[cls + 1] - kb;
    int nch = len >> 6;                       // BK=64 chunks (len is 64-padded)
    int s = blockIdx.z;
    int ch0 = (nch * s) / SPL, ch1 = (nch * (s + 1)) / SPL;
    if (ch0 >= ch1) return;

    int t = threadIdx.x;
    int lane = t & 63, wave = t >> 6;
    int wro = (wave >> 1) * 64, wco = (wave & 1) * 64;

    f32x4 acc[4][4] = {};

    int sr = t >> 1;                 // staging row 0..127
    int sq = (t & 1) * 32;           // elem offset 0 / 32  (two 64B halves of 128B row)

    for (int ch = ch0; ch < ch1; ++ch) {
        int k0 = kb + ch * 64;
        const uint4* ga = (const uint4*)(Xst + (size_t)(ti * 128 + sr) * XP + k0 + sq);
        const uint4* gb = (const uint4*)(Xst + (size_t)(tj * 128 + sr) * XP + k0 + sq);
        uint4 a0 = ga[0], a1 = ga[1], a2 = ga[2], a3 = ga[3];   // 4x8 bf16 = 32 elems
        uint4 b0 = gb[0], b1 = gb[1], b2 = gb[2], b3 = gb[3];
        __syncthreads();                      // previous-chunk readers done
        *(uint4*)&sA[sr][sq]      = a0;
        *(uint4*)&sA[sr][sq + 8]  = a1;
        *(uint4*)&sA[sr][sq + 16] = a2;
        *(uint4*)&sA[sr][sq + 24] = a3;
        *(uint4*)&sB[sr][sq]      = b0;
        *(uint4*)&sB[sr][sq + 8]  = b1;
        *(uint4*)&sB[sr][sq + 16] = b2;
        *(uint4*)&sB[sr][sq + 24] = b3;
        __syncthreads();
        #pragma unroll
        for (int ks = 0; ks < 64; ks += 32) {
            bf16x8 af[4], bfr[4];
            #pragma unroll
            for (int r = 0; r < 4; ++r)
                af[r] = *(const bf16x8*)&sA[wro + r * 16 + (lane & 15)][ks + (lane >> 4) * 8];
            #pragma unroll
            for (int c2 = 0; c2 < 4; ++c2)
                bfr[c2] = *(const bf16x8*)&sB[wco + c2 * 16 + (lane & 15)][ks + (lane >> 4) * 8];
            #pragma unroll
            for (int r = 0; r < 4; ++r) {
                #pragma unroll
                for (int c2 = 0; c2 < 4; ++c2)
                    acc[r][c2] = __builtin_amdgcn_mfma_f32_16x16x32_bf16(af[r], bfr[c2], acc[r][c2], 0, 0, 0);
            }
        }
    }

    float* cb = cov + (size_t)cls * (N_COLS * N_COLS);
    int prow = ti * 128 + wro + ((lane >> 4) << 2);
    int pcol = tj * 128 + wco + (lane & 15);
    #pragma unroll
    for (int r = 0; r < 4; ++r) {
        #pragma unroll
        for (int c2 = 0; c2 < 4; ++c2) {
            #pragma unroll
            for (int v = 0; v < 4; ++v)
                atomicAdd(&cb[(size_t)(prow + r * 16 + v) * N_COLS + pcol + c2 * 16], acc[r][c2][v]);
        }
    }
}

// ---------------- LDL^T logdet ----------------
// cov storage: 128-blocks (0,0),(0,1),(1,1) present; (1,0) mirrored on read.
__global__ __launch_bounds__(1024) void ldl_kernel(const float* __restrict__ cov,
                                                   const int* __restrict__ meta,
                                                   float* __restrict__ logdets) {
    int b = blockIdx.x;   // 0..10
    int t = threadIdx.x;
    int i = t >> 2;       // row
    int q = t & 3;
    int c0 = q * 64;

    float scal;
    if (b < NCLASS) scal = (float)N_COLS / (((float)meta[32 + b] + 1e-8f) * 0.01f);
    else            scal = (float)N_COLS / ((float)N_ROWS * 0.01f);

    float r[64];
    #pragma unroll
    for (int v = 0; v < 64; ++v) {
        int c = c0 + v;
        int a0 = i, b0 = c;
        if ((i >> 7) > (c >> 7)) { a0 = c; b0 = i; }
        size_t off = (size_t)a0 * N_COLS + b0;
        float sv;
        if (b < NCLASS) {
            sv = cov[(size_t)b * (N_COLS * N_COLS) + off];
        } else {
            sv = 0.f;
            #pragma unroll
            for (int k = 0; k < NCLASS; ++k)
                sv += cov[(size_t)k * (N_COLS * N_COLS) + off];
        }
        r[v] = scal * sv + ((c == i) ? 1.f : 0.f);
    }

    __shared__ float rowbuf[2][256];
    float logsum = 0.f;
    for (int j = 0; j < N_COLS; ++j) {
        float* row = rowbuf[j & 1];
        if (i == j) {   // raw b128 publish; sub-j positions are dead and never leak
            #pragma unroll
            for (int v = 0; v < 64; v += 4) {
                float4 t4 = make_float4(r[v], r[v + 1], r[v + 2], r[v + 3]);
                *(float4*)&row[c0 + v] = t4;
            }
        }
        __syncthreads();   // single barrier/step: 2-buffer makes next publish safe
        float d = row[j];
        logsum += __logf(d);
        if (i > j) {
            float s = row[i] / d;
            #pragma unroll
            for (int v = 0; v < 64; v += 4) {
                float4 rv = *(const float4*)&row[c0 + v];
                r[v]     -= s * rv.x;
                r[v + 1] -= s * rv.y;
                r[v + 2] -= s * rv.z;
                r[v + 3] -= s * rv.w;
            }
        }
    }
    if (t == 0) logdets[b] = logsum;
}

// ---------------- finalize ----------------
__global__ void finalize_kernel(const float* __restrict__ logdets,
                                const int* __restrict__ meta,
                                float* __restrict__ out) {
    if (threadIdx.x == 0 && blockIdx.x == 0) {
        float discrimn = 0.5f * logdets[NCLASS];      // GAM1 == 1 => empi == theo
        float compress = 0.f;
        for (int k = 0; k < NCLASS; ++k) {
            float tr = (float)meta[32 + k] + 1e-8f;
            compress += logdets[k] * tr;
        }
        compress = compress / (float)N_ROWS * 0.5f;
        out[0] = -discrimn + compress;                // GAM2 == 1
        out[1] = discrimn;
        out[2] = compress;
        out[3] = discrimn;
        out[4] = compress;
    }
}

extern "C" void kernel_launch(void* const* d_in, const int* in_sizes, int n_in,
                              void* d_out, int out_size, void* d_ws, size_t ws_size,
                              hipStream_t stream) {
    const float* X = (const float*)d_in[0];
    const int*   Y = (const int*)d_in[1];
    float* out = (float*)d_out;

    char* ws = (char*)d_ws;
    const size_t o_cov   = 0;                        // 10*256*256*4 = 2,621,440
    const size_t o_meta  = 2621440;                  // 64 ints
    const size_t o_blkc  = o_meta + 256;             // 2560 ints
    const size_t o_blkb  = o_blkc + 10240;           // 2560 ints
    const size_t o_order = o_blkb + 10240;           // 65536 ints
    const size_t o_logd  = o_order + 262144;         // 16 floats
    const size_t o_xst   = o_logd + 256;             // 256*XP*2 = 33,882,112

    float*          cov      = (float*)(ws + o_cov);
    int*            meta     = (int*)(ws + o_meta);
    int*            blk_cnt  = (int*)(ws + o_blkc);
    int*            blk_base = (int*)(ws + o_blkb);
    int*            order    = (int*)(ws + o_order);
    float*          logdets  = (float*)(ws + o_logd);
    unsigned short* Xst      = (unsigned short*)(ws + o_xst);

    hipMemsetAsync(cov, 0, (size_t)NCLASS * N_COLS * N_COLS * sizeof(float), stream);
    hipLaunchKernelGGL(blkhist_kernel, dim3(256), dim3(256), 0, stream, Y, blk_cnt);
    hipLaunchKernelGGL(scan_kernel, dim3(1), dim3(256), 0, stream, blk_cnt, meta, blk_base);
    hipLaunchKernelGGL(order_kernel, dim3(256), dim3(256), 0, stream, Y, blk_base, order);
    hipLaunchKernelGGL(gather_kernel, dim3(XP / 64), dim3(256), 0, stream, X, order, meta, Xst);
    hipLaunchKernelGGL(cov_mfma, dim3(3, NCLASS, SPL), dim3(256), 0, stream, Xst, meta, cov);
    hipLaunchKernelGGL(ldl_kernel, dim3(11), dim3(1024), 0, stream, cov, meta, logdets);
    hipLaunchKernelGGL(finalize_kernel, dim3(1), dim3(64), 0, stream, logdets, meta, out);
}

// Round 4
// 400.753 us; speedup vs baseline: 4.9892x; 1.8466x over previous
//
#include <hip/hip_runtime.h>

#define N_ROWS 65536
#define N_COLS 256
#define NCLASS 10
#define XP 66176            // Xst col pitch: 65536 + 10*64 pad
#define SPL 16              // K-splits per (class,tile)

typedef __attribute__((ext_vector_type(8))) short bf16x8;
typedef __attribute__((ext_vector_type(4))) float f32x4;

// meta layout (ints): [0..10] off_pad, [16..26] offsets (unpadded), [32..41] counts

static __device__ __forceinline__ unsigned short f2bf(float f) {
    unsigned int u = __float_as_uint(f);
    unsigned int r = (u + 0x7FFFu + ((u >> 16) & 1u)) >> 16;   // RTN-even
    return (unsigned short)r;
}

// ---------------- Phase A: per-block class histogram ----------------
__global__ __launch_bounds__(256) void blkhist_kernel(const int* __restrict__ Y,
                                                      int* __restrict__ blk_cnt) {
    __shared__ int h[NCLASS];
    int b = blockIdx.x, t = threadIdx.x;
    if (t < NCLASS) h[t] = 0;
    __syncthreads();
    atomicAdd(&h[Y[b * 256 + t]], 1);
    __syncthreads();
    if (t < NCLASS) blk_cnt[b * NCLASS + t] = h[t];
}

// ---------------- Phase B: scan -> meta + per-block bases ----------------
__global__ __launch_bounds__(256) void scan_kernel(const int* __restrict__ blk_cnt,
                                                   int* __restrict__ meta,
                                                   int* __restrict__ blk_base) {
    __shared__ int sc[256 * NCLASS];
    __shared__ int tots[16];
    __shared__ int soff[16];
    int t = threadIdx.x;
    for (int j = t; j < 256 * NCLASS; j += 256) sc[j] = blk_cnt[j];
    __syncthreads();
    if (t < NCLASS) {
        int s = 0;
        for (int b = 0; b < 256; ++b) s += sc[b * NCLASS + t];
        tots[t] = s;
    }
    __syncthreads();
    if (t == 0) {
        int off = 0, offp = 0;
        for (int c = 0; c < NCLASS; ++c) {
            soff[c] = off;
            meta[16 + c] = off;
            meta[c] = offp;
            meta[32 + c] = tots[c];
            off += tots[c];
            offp += (tots[c] + 63) & ~63;
        }
        meta[16 + NCLASS] = off;
        meta[NCLASS] = offp;
    }
    __syncthreads();
    if (t < NCLASS) {
        int run = soff[t];
        for (int b = 0; b < 256; ++b) {
            blk_base[b * NCLASS + t] = run;
            run += sc[b * NCLASS + t];
        }
    }
}

// ---------------- Phase C: build sorted order ----------------
__global__ __launch_bounds__(256) void order_kernel(const int* __restrict__ Y,
                                                    const int* __restrict__ blk_base,
                                                    int* __restrict__ order) {
    __shared__ int lcur[NCLASS];
    int b = blockIdx.x, t = threadIdx.x;
    if (t < NCLASS) lcur[t] = 0;
    __syncthreads();
    int i = b * 256 + t;
    int y = Y[i];
    int pos = blk_base[b * NCLASS + y] + atomicAdd(&lcur[y], 1);
    order[pos] = i;
}

// ---------------- Phase D: gather + fp32->bf16 + transpose ----------------
__global__ __launch_bounds__(256) void gather_kernel(const float* __restrict__ X,
                                                     const int* __restrict__ order,
                                                     const int* __restrict__ meta,
                                                     unsigned short* __restrict__ Xst) {
    __shared__ unsigned short sT[256 * 72];   // pitch 72 shorts = 144B (16B-aligned rows)
    int p0 = blockIdx.x * 64;
    if (p0 >= meta[NCLASS]) return;
    int cls = 0;
    while (p0 >= meta[cls + 1]) ++cls;       // 64-tiles never straddle classes
    int lp0 = p0 - meta[cls];
    int cnt = meta[32 + cls];
    int obase = meta[16 + cls];

    int t = threadIdx.x;
    int p = t >> 2;                 // 0..63 local pos
    int cseg = (t & 3) * 64;        // feature segment
    int lp = lp0 + p;
    int row = (lp < cnt) ? order[obase + lp] : -1;
    const float* xr = X + (size_t)(row < 0 ? 0 : row) * N_COLS;
    #pragma unroll
    for (int k = 0; k < 16; ++k) {
        int col = cseg + k * 4;
        float4 v;
        if (row >= 0) v = *(const float4*)(xr + col);
        else          v = make_float4(0.f, 0.f, 0.f, 0.f);
        sT[(col + 0) * 72 + p] = f2bf(v.x);
        sT[(col + 1) * 72 + p] = f2bf(v.y);
        sT[(col + 2) * 72 + p] = f2bf(v.z);
        sT[(col + 3) * 72 + p] = f2bf(v.w);
    }
    __syncthreads();
    // vectorized writeout: 16B/lane (ds_read_b128 + global_store_dwordx4)
    int pc = t & 7;          // pos-chunk 0..7 (8 shorts each)
    int cb = t >> 3;         // col base 0..31
    #pragma unroll
    for (int j = 0; j < 8; ++j) {
        int col = cb + j * 32;
        uint4 v = *(const uint4*)&sT[col * 72 + pc * 8];
        *(uint4*)(Xst + (size_t)col * XP + p0 + pc * 8) = v;
    }
}

// ---------------- cov via bf16 MFMA syrk ----------------
__global__ __launch_bounds__(256) void cov_mfma(const unsigned short* __restrict__ Xst,
                                                const int* __restrict__ meta,
                                                float* __restrict__ cov) {
    __shared__ unsigned short sA[128][72];
    __shared__ unsigned short sB[128][72];
    int cls = blockIdx.y;
    int tile = blockIdx.x;
    int ti = (tile == 2) ? 1 : 0;
    int tj = (tile == 0) ? 0 : 1;
    int kb = meta[cls];
    int len = meta[cls + 1] - kb;
    int nch = len >> 6;
    int s = blockIdx.z;
    int ch0 = (nch * s) / SPL, ch1 = (nch * (s + 1)) / SPL;
    if (ch0 >= ch1) return;

    int t = threadIdx.x;
    int lane = t & 63, wave = t >> 6;
    int wro = (wave >> 1) * 64, wco = (wave & 1) * 64;

    f32x4 acc[4][4] = {};

    int sr = t >> 1;
    int sq = (t & 1) * 32;

    for (int ch = ch0; ch < ch1; ++ch) {
        int k0 = kb + ch * 64;
        const uint4* ga = (const uint4*)(Xst + (size_t)(ti * 128 + sr) * XP + k0 + sq);
        const uint4* gb = (const uint4*)(Xst + (size_t)(tj * 128 + sr) * XP + k0 + sq);
        uint4 a0 = ga[0], a1 = ga[1], a2 = ga[2], a3 = ga[3];
        uint4 b0 = gb[0], b1 = gb[1], b2 = gb[2], b3 = gb[3];
        __syncthreads();
        *(uint4*)&sA[sr][sq]      = a0;
        *(uint4*)&sA[sr][sq + 8]  = a1;
        *(uint4*)&sA[sr][sq + 16] = a2;
        *(uint4*)&sA[sr][sq + 24] = a3;
        *(uint4*)&sB[sr][sq]      = b0;
        *(uint4*)&sB[sr][sq + 8]  = b1;
        *(uint4*)&sB[sr][sq + 16] = b2;
        *(uint4*)&sB[sr][sq + 24] = b3;
        __syncthreads();
        #pragma unroll
        for (int ks = 0; ks < 64; ks += 32) {
            bf16x8 af[4], bfr[4];
            #pragma unroll
            for (int r = 0; r < 4; ++r)
                af[r] = *(const bf16x8*)&sA[wro + r * 16 + (lane & 15)][ks + (lane >> 4) * 8];
            #pragma unroll
            for (int c2 = 0; c2 < 4; ++c2)
                bfr[c2] = *(const bf16x8*)&sB[wco + c2 * 16 + (lane & 15)][ks + (lane >> 4) * 8];
            #pragma unroll
            for (int r = 0; r < 4; ++r) {
                #pragma unroll
                for (int c2 = 0; c2 < 4; ++c2)
                    acc[r][c2] = __builtin_amdgcn_mfma_f32_16x16x32_bf16(af[r], bfr[c2], acc[r][c2], 0, 0, 0);
            }
        }
    }

    float* cb = cov + (size_t)cls * (N_COLS * N_COLS);
    int prow = ti * 128 + wro + ((lane >> 4) << 2);
    int pcol = tj * 128 + wco + (lane & 15);
    #pragma unroll
    for (int r = 0; r < 4; ++r) {
        #pragma unroll
        for (int c2 = 0; c2 < 4; ++c2) {
            #pragma unroll
            for (int v = 0; v < 4; ++v)
                atomicAdd(&cb[(size_t)(prow + r * 16 + v) * N_COLS + pcol + c2 * 16], acc[r][c2][v]);
        }
    }
}

// ---------------- blocked LDL^T logdet (nb=8, symmetric lower-tri tiles) ----------------
// 576 threads; threads 0..527 own 8x8 lower-tri tile (ti,tj), tj<=ti, in registers.
// Per panel k: stripe (tj==k) -> LDS panel (dbuf'd); wave0 factors panel in regs via
// shuffles (U[jj][c] = d[jj]*L[c][jj] -- no separate U solve); trailing tiles do
// rank-8 register-blocked update (16 FMA per LDS float read).
#define RBP 68   // floats per 8-row block in pan (68: spreads rowblocks across banks)
__global__ __launch_bounds__(576) void ldl_kernel(const float* __restrict__ cov,
                                                  const int* __restrict__ meta,
                                                  float* __restrict__ logdets) {
    int b = blockIdx.x;   // 0..10
    int tt = threadIdx.x;
    bool owner = (tt < 528);
    int ti = 0, tj = 0;
    if (owner) {
        ti = (int)((sqrtf(8.f * (float)tt + 1.f) - 1.f) * 0.5f);
        while ((ti + 1) * (ti + 2) / 2 <= tt) ++ti;
        while (ti * (ti + 1) / 2 > tt) --ti;
        tj = tt - ti * (ti + 1) / 2;
    }

    float scal;
    if (b < NCLASS) scal = (float)N_COLS / (((float)meta[32 + b] + 1e-8f) * 0.01f);
    else            scal = (float)N_COLS / ((float)N_ROWS * 0.01f);

    float tile[64];
    if (owner) {
        bool mir = (ti >= 16) && (tj < 16);   // cov stores upper 128-blocks; mirror (1,0)
        if (!mir) {
            #pragma unroll
            for (int rr = 0; rr < 8; ++rr) {
                size_t rowoff = (size_t)(8 * ti + rr) * N_COLS + 8 * tj;
                #pragma unroll
                for (int q4 = 0; q4 < 2; ++q4) {
                    float4 v = make_float4(0.f, 0.f, 0.f, 0.f);
                    if (b < NCLASS) {
                        v = *(const float4*)(cov + (size_t)b * 65536 + rowoff + q4 * 4);
                    } else {
                        #pragma unroll
                        for (int cl = 0; cl < NCLASS; ++cl) {
                            float4 w = *(const float4*)(cov + (size_t)cl * 65536 + rowoff + q4 * 4);
                            v.x += w.x; v.y += w.y; v.z += w.z; v.w += w.w;
                        }
                    }
                    tile[rr * 8 + q4 * 4 + 0] = v.x;
                    tile[rr * 8 + q4 * 4 + 1] = v.y;
                    tile[rr * 8 + q4 * 4 + 2] = v.z;
                    tile[rr * 8 + q4 * 4 + 3] = v.w;
                }
            }
        } else {
            #pragma unroll
            for (int cc = 0; cc < 8; ++cc) {
                size_t coloff = (size_t)(8 * tj + cc) * N_COLS + 8 * ti;
                #pragma unroll
                for (int q4 = 0; q4 < 2; ++q4) {
                    float4 v = make_float4(0.f, 0.f, 0.f, 0.f);
                    if (b < NCLASS) {
                        v = *(const float4*)(cov + (size_t)b * 65536 + coloff + q4 * 4);
                    } else {
                        #pragma unroll
                        for (int cl = 0; cl < NCLASS; ++cl) {
                            float4 w = *(const float4*)(cov + (size_t)cl * 65536 + coloff + q4 * 4);
                            v.x += w.x; v.y += w.y; v.z += w.z; v.w += w.w;
                        }
                    }
                    tile[(q4 * 4 + 0) * 8 + cc] = v.x;
                    tile[(q4 * 4 + 1) * 8 + cc] = v.y;
                    tile[(q4 * 4 + 2) * 8 + cc] = v.z;
                    tile[(q4 * 4 + 3) * 8 + cc] = v.w;
                }
            }
        }
        #pragma unroll
        for (int rr = 0; rr < 8; ++rr)
            #pragma unroll
            for (int cc = 0; cc < 8; ++cc)
                tile[rr * 8 + cc] = scal * tile[rr * 8 + cc]
                                  + ((ti == tj && rr == cc) ? 1.f : 0.f);
    }

    __shared__ float pan[2][32 * RBP];   // addr(r,c) = (r>>3)*RBP + (r&7)*8 + c
    __shared__ float dbuf[8];
    float dlogsum = 0.f;                 // identical across wave0 lanes

    for (int k = 0; k < 32; ++k) {
        float* pb = pan[k & 1];
        // --- stripe write (tj == k implies ti >= k) ---
        if (owner && tj == k) {
            #pragma unroll
            for (int rr = 0; rr < 8; ++rr) {
                *(float4*)&pb[ti * RBP + rr * 8]     = make_float4(tile[rr*8+0], tile[rr*8+1], tile[rr*8+2], tile[rr*8+3]);
                *(float4*)&pb[ti * RBP + rr * 8 + 4] = make_float4(tile[rr*8+4], tile[rr*8+5], tile[rr*8+6], tile[rr*8+7]);
            }
        }
        __syncthreads();   // A: stripe visible; prior trailing done before reuse of pb
        // --- wave0: factor panel in registers via shuffles ---
        if (tt < 64) {
            int l = tt;
            float preg[4][8];
            bool valid[4];
            #pragma unroll
            for (int s = 0; s < 4; ++s) {
                int rg = 8 * k + 64 * s + l;          // global row
                valid[s] = (rg < 256);
                if (valid[s]) {
                    int base = (rg >> 3) * RBP + (rg & 7) * 8;
                    float4 lo = *(const float4*)&pb[base];
                    float4 hi = *(const float4*)&pb[base + 4];
                    preg[s][0] = lo.x; preg[s][1] = lo.y; preg[s][2] = lo.z; preg[s][3] = lo.w;
                    preg[s][4] = hi.x; preg[s][5] = hi.y; preg[s][6] = hi.z; preg[s][7] = hi.w;
                }
            }
            #pragma unroll
            for (int jj = 0; jj < 8; ++jj) {
                float pv[8];
                #pragma unroll
                for (int cc = 0; cc < 8; ++cc) pv[cc] = __shfl(preg[0][cc], jj, 64);
                float d = pv[jj];
                dlogsum += __logf(d);
                if (l == jj) dbuf[jj] = d;
                float rd = 1.0f / d;
                #pragma unroll
                for (int s = 0; s < 4; ++s) {
                    int prl = 64 * s + l;             // local panel row
                    if (valid[s] && prl > jj) {
                        float lm = preg[s][jj] * rd;
                        preg[s][jj] = lm;
                        #pragma unroll
                        for (int cc = jj + 1; cc < 8; ++cc)
                            preg[s][cc] -= lm * pv[cc];
                    }
                }
            }
            #pragma unroll
            for (int s = 0; s < 4; ++s) {
                if (valid[s]) {
                    int rg = 8 * k + 64 * s + l;
                    int base = (rg >> 3) * RBP + (rg & 7) * 8;
                    *(float4*)&pb[base]     = make_float4(preg[s][0], preg[s][1], preg[s][2], preg[s][3]);
                    *(float4*)&pb[base + 4] = make_float4(preg[s][4], preg[s][5], preg[s][6], preg[s][7]);
                }
            }
        }
        __syncthreads();   // B: factored panel + dbuf visible
        // --- trailing rank-8 update: A -= L_ti * D * L_tj^T ---
        if (owner && tj > k) {
            float dvv[8];
            #pragma unroll
            for (int jj = 0; jj < 8; ++jj) dvv[jj] = dbuf[jj];
            float ldc[64];   // ldc[cc][jj] = d[jj] * L[8tj+cc][jj]
            #pragma unroll
            for (int cc = 0; cc < 8; ++cc) {
                float4 lo = *(const float4*)&pb[tj * RBP + cc * 8];
                float4 hi = *(const float4*)&pb[tj * RBP + cc * 8 + 4];
                ldc[cc * 8 + 0] = lo.x * dvv[0];
                ldc[cc * 8 + 1] = lo.y * dvv[1];
                ldc[cc * 8 + 2] = lo.z * dvv[2];
                ldc[cc * 8 + 3] = lo.w * dvv[3];
                ldc[cc * 8 + 4] = hi.x * dvv[4];
                ldc[cc * 8 + 5] = hi.y * dvv[5];
                ldc[cc * 8 + 6] = hi.z * dvv[6];
                ldc[cc * 8 + 7] = hi.w * dvv[7];
            }
            #pragma unroll
            for (int rr = 0; rr < 8; ++rr) {
                float4 lo = *(const float4*)&pb[ti * RBP + rr * 8];
                float4 hi = *(const float4*)&pb[ti * RBP + rr * 8 + 4];
                float lr[8] = {lo.x, lo.y, lo.z, lo.w, hi.x, hi.y, hi.z, hi.w};
                #pragma unroll
                for (int cc = 0; cc < 8; ++cc) {
                    float s = lr[0] * ldc[cc * 8 + 0];
                    #pragma unroll
                    for (int jj = 1; jj < 8; ++jj)
                        s = fmaf(lr[jj], ldc[cc * 8 + jj], s);
                    tile[rr * 8 + cc] -= s;
                }
            }
        }
    }
    if (tt == 0) logdets[b] = dlogsum;
}

// ---------------- finalize ----------------
__global__ void finalize_kernel(const float* __restrict__ logdets,
                                const int* __restrict__ meta,
                                float* __restrict__ out) {
    if (threadIdx.x == 0 && blockIdx.x == 0) {
        float discrimn = 0.5f * logdets[NCLASS];      // GAM1 == 1 => empi == theo
        float compress = 0.f;
        for (int k = 0; k < NCLASS; ++k) {
            float tr = (float)meta[32 + k] + 1e-8f;
            compress += logdets[k] * tr;
        }
        compress = compress / (float)N_ROWS * 0.5f;
        out[0] = -discrimn + compress;                // GAM2 == 1
        out[1] = discrimn;
        out[2] = compress;
        out[3] = discrimn;
        out[4] = compress;
    }
}

extern "C" void kernel_launch(void* const* d_in, const int* in_sizes, int n_in,
                              void* d_out, int out_size, void* d_ws, size_t ws_size,
                              hipStream_t stream) {
    const float* X = (const float*)d_in[0];
    const int*   Y = (const int*)d_in[1];
    float* out = (float*)d_out;

    char* ws = (char*)d_ws;
    const size_t o_cov   = 0;                        // 10*256*256*4 = 2,621,440
    const size_t o_meta  = 2621440;                  // 64 ints
    const size_t o_blkc  = o_meta + 256;             // 2560 ints
    const size_t o_blkb  = o_blkc + 10240;           // 2560 ints
    const size_t o_order = o_blkb + 10240;           // 65536 ints
    const size_t o_logd  = o_order + 262144;         // 16 floats
    const size_t o_xst   = o_logd + 256;             // 256*XP*2 = 33,882,112

    float*          cov      = (float*)(ws + o_cov);
    int*            meta     = (int*)(ws + o_meta);
    int*            blk_cnt  = (int*)(ws + o_blkc);
    int*            blk_base = (int*)(ws + o_blkb);
    int*            order    = (int*)(ws + o_order);
    float*          logdets  = (float*)(ws + o_logd);
    unsigned short* Xst      = (unsigned short*)(ws + o_xst);

    hipMemsetAsync(cov, 0, (size_t)NCLASS * N_COLS * N_COLS * sizeof(float), stream);
    hipLaunchKernelGGL(blkhist_kernel, dim3(256), dim3(256), 0, stream, Y, blk_cnt);
    hipLaunchKernelGGL(scan_kernel, dim3(1), dim3(256), 0, stream, blk_cnt, meta, blk_base);
    hipLaunchKernelGGL(order_kernel, dim3(256), dim3(256), 0, stream, Y, blk_base, order);
    hipLaunchKernelGGL(gather_kernel, dim3(XP / 64), dim3(256), 0, stream, X, order, meta, Xst);
    hipLaunchKernelGGL(cov_mfma, dim3(3, NCLASS, SPL), dim3(256), 0, stream, Xst, meta, cov);
    hipLaunchKernelGGL(ldl_kernel, dim3(11), dim3(576), 0, stream, cov, meta, logdets);
    hipLaunchKernelGGL(finalize_kernel, dim3(1), dim3(64), 0, stream, logdets, meta, out);
}

// Round 5
// 328.013 us; speedup vs baseline: 6.0956x; 1.2218x over previous
//
#include <hip/hip_runtime.h>

#define N_ROWS 65536
#define N_COLS 256
#define NCLASS 10
#define XP 66176            // Xst col pitch: 65536 + 10*64 pad
#define SPL 16              // K-splits per (class,tile)
#define MSZ 65536           // 256*256 elements per matrix

typedef __attribute__((ext_vector_type(8))) short bf16x8;
typedef __attribute__((ext_vector_type(4))) float f32x4;

// meta layout (ints): [0..10] off_pad, [16..26] offsets (unpadded), [32..41] counts
// slab layout (bf16): s*11*MSZ + m*MSZ for s in {0:E,1:G=E^2,2:H=E^3,3:K=E^4,4:P=E^6}

static __device__ __forceinline__ unsigned short f2bf(float f) {
    unsigned int u = __float_as_uint(f);
    unsigned int r = (u + 0x7FFFu + ((u >> 16) & 1u)) >> 16;   // RTN-even
    return (unsigned short)r;
}
static __device__ __forceinline__ float bf2f(unsigned short s) {
    return __uint_as_float(((unsigned int)s) << 16);
}
static __device__ __forceinline__ void unpack8(const unsigned short* p, float* f) {
    uint4 u = *(const uint4*)p;
    f[0] = __uint_as_float(u.x << 16); f[1] = __uint_as_float(u.x & 0xffff0000u);
    f[2] = __uint_as_float(u.y << 16); f[3] = __uint_as_float(u.y & 0xffff0000u);
    f[4] = __uint_as_float(u.z << 16); f[5] = __uint_as_float(u.z & 0xffff0000u);
    f[6] = __uint_as_float(u.w << 16); f[7] = __uint_as_float(u.w & 0xffff0000u);
}

// ---------------- Phase A: per-block class histogram ----------------
__global__ __launch_bounds__(256) void blkhist_kernel(const int* __restrict__ Y,
                                                      int* __restrict__ blk_cnt) {
    __shared__ int h[NCLASS];
    int b = blockIdx.x, t = threadIdx.x;
    if (t < NCLASS) h[t] = 0;
    __syncthreads();
    atomicAdd(&h[Y[b * 256 + t]], 1);
    __syncthreads();
    if (t < NCLASS) blk_cnt[b * NCLASS + t] = h[t];
}

// ---------------- Phase B: scan (wave-per-class shuffle scans) ----------------
__global__ __launch_bounds__(1024) void scan_kernel(const int* __restrict__ blk_cnt,
                                                    int* __restrict__ meta,
                                                    int* __restrict__ blk_base) {
    int t = threadIdx.x;
    int w = t >> 6, l = t & 63;
    __shared__ int tots[16];
    __shared__ int soff_s[16];
    int s0 = 0, s1 = 0, s2 = 0, s3 = 0;
    if (w < NCLASS) {
        s0 = blk_cnt[(l      ) * NCLASS + w];
        s1 = blk_cnt[(l +  64) * NCLASS + w];
        s2 = blk_cnt[(l + 128) * NCLASS + w];
        s3 = blk_cnt[(l + 192) * NCLASS + w];
    }
    int x0 = s0, x1 = s1, x2 = s2, x3 = s3;
    for (int d = 1; d < 64; d <<= 1) {
        int y0 = __shfl_up(x0, d, 64), y1 = __shfl_up(x1, d, 64);
        int y2 = __shfl_up(x2, d, 64), y3 = __shfl_up(x3, d, 64);
        if (l >= d) { x0 += y0; x1 += y1; x2 += y2; x3 += y3; }
    }
    int T0 = __shfl(x0, 63, 64), T1 = __shfl(x1, 63, 64);
    int T2 = __shfl(x2, 63, 64), T3 = __shfl(x3, 63, 64);
    if (w < NCLASS && l == 63) tots[w] = T0 + T1 + T2 + T3;
    __syncthreads();
    if (t == 0) {
        int off = 0, offp = 0;
        for (int c = 0; c < NCLASS; ++c) {
            soff_s[c] = off;
            meta[16 + c] = off;
            meta[c] = offp;
            meta[32 + c] = tots[c];
            off += tots[c];
            offp += (tots[c] + 63) & ~63;
        }
        meta[16 + NCLASS] = off;
        meta[NCLASS] = offp;
    }
    __syncthreads();
    if (w < NCLASS) {
        int base = soff_s[w];
        blk_base[(l      ) * NCLASS + w] = base + x0 - s0;
        blk_base[(l +  64) * NCLASS + w] = base + T0 + x1 - s1;
        blk_base[(l + 128) * NCLASS + w] = base + T0 + T1 + x2 - s2;
        blk_base[(l + 192) * NCLASS + w] = base + T0 + T1 + T2 + x3 - s3;
    }
}

// ---------------- Phase C: build sorted order ----------------
__global__ __launch_bounds__(256) void order_kernel(const int* __restrict__ Y,
                                                    const int* __restrict__ blk_base,
                                                    int* __restrict__ order) {
    __shared__ int lcur[NCLASS];
    int b = blockIdx.x, t = threadIdx.x;
    if (t < NCLASS) lcur[t] = 0;
    __syncthreads();
    int i = b * 256 + t;
    int y = Y[i];
    int pos = blk_base[b * NCLASS + y] + atomicAdd(&lcur[y], 1);
    order[pos] = i;
}

// ---------------- Phase D: gather + fp32->bf16 + transpose ----------------
__global__ __launch_bounds__(256) void gather_kernel(const float* __restrict__ X,
                                                     const int* __restrict__ order,
                                                     const int* __restrict__ meta,
                                                     unsigned short* __restrict__ Xst) {
    __shared__ unsigned short sT[256 * 72];   // pitch 72 shorts = 144B (16B-aligned rows)
    int p0 = blockIdx.x * 64;
    if (p0 >= meta[NCLASS]) return;
    int cls = 0;
    while (p0 >= meta[cls + 1]) ++cls;       // 64-tiles never straddle classes
    int lp0 = p0 - meta[cls];
    int cnt = meta[32 + cls];
    int obase = meta[16 + cls];

    int t = threadIdx.x;
    int p = t >> 2;                 // 0..63 local pos
    int cseg = (t & 3) * 64;        // feature segment
    int lp = lp0 + p;
    int row = (lp < cnt) ? order[obase + lp] : -1;
    const float* xr = X + (size_t)(row < 0 ? 0 : row) * N_COLS;
    #pragma unroll
    for (int k = 0; k < 16; ++k) {
        int col = cseg + k * 4;
        float4 v;
        if (row >= 0) v = *(const float4*)(xr + col);
        else          v = make_float4(0.f, 0.f, 0.f, 0.f);
        sT[(col + 0) * 72 + p] = f2bf(v.x);
        sT[(col + 1) * 72 + p] = f2bf(v.y);
        sT[(col + 2) * 72 + p] = f2bf(v.z);
        sT[(col + 3) * 72 + p] = f2bf(v.w);
    }
    __syncthreads();
    int pc = t & 7;          // pos-chunk 0..7 (8 shorts each)
    int cb = t >> 3;         // col base 0..31
    #pragma unroll
    for (int j = 0; j < 8; ++j) {
        int col = cb + j * 32;
        uint4 v = *(const uint4*)&sT[col * 72 + pc * 8];
        *(uint4*)(Xst + (size_t)col * XP + p0 + pc * 8) = v;
    }
}

// ---------------- cov via bf16 MFMA syrk ----------------
__global__ __launch_bounds__(256) void cov_mfma(const unsigned short* __restrict__ Xst,
                                                const int* __restrict__ meta,
                                                float* __restrict__ cov) {
    __shared__ unsigned short sA[128][72];
    __shared__ unsigned short sB[128][72];
    int cls = blockIdx.y;
    int tile = blockIdx.x;
    int ti = (tile == 2) ? 1 : 0;
    int tj = (tile == 0) ? 0 : 1;
    int kb = meta[cls];
    int len = meta[cls + 1] - kb;
    int nch = len >> 6;
    int s = blockIdx.z;
    int ch0 = (nch * s) / SPL, ch1 = (nch * (s + 1)) / SPL;
    if (ch0 >= ch1) return;

    int t = threadIdx.x;
    int lane = t & 63, wave = t >> 6;
    int wro = (wave >> 1) * 64, wco = (wave & 1) * 64;

    f32x4 acc[4][4] = {};

    int sr = t >> 1;
    int sq = (t & 1) * 32;

    for (int ch = ch0; ch < ch1; ++ch) {
        int k0 = kb + ch * 64;
        const uint4* ga = (const uint4*)(Xst + (size_t)(ti * 128 + sr) * XP + k0 + sq);
        const uint4* gb = (const uint4*)(Xst + (size_t)(tj * 128 + sr) * XP + k0 + sq);
        uint4 a0 = ga[0], a1 = ga[1], a2 = ga[2], a3 = ga[3];
        uint4 b0 = gb[0], b1 = gb[1], b2 = gb[2], b3 = gb[3];
        __syncthreads();
        *(uint4*)&sA[sr][sq]      = a0;
        *(uint4*)&sA[sr][sq + 8]  = a1;
        *(uint4*)&sA[sr][sq + 16] = a2;
        *(uint4*)&sA[sr][sq + 24] = a3;
        *(uint4*)&sB[sr][sq]      = b0;
        *(uint4*)&sB[sr][sq + 8]  = b1;
        *(uint4*)&sB[sr][sq + 16] = b2;
        *(uint4*)&sB[sr][sq + 24] = b3;
        __syncthreads();
        #pragma unroll
        for (int ks = 0; ks < 64; ks += 32) {
            bf16x8 af[4], bfr[4];
            #pragma unroll
            for (int r = 0; r < 4; ++r)
                af[r] = *(const bf16x8*)&sA[wro + r * 16 + (lane & 15)][ks + (lane >> 4) * 8];
            #pragma unroll
            for (int c2 = 0; c2 < 4; ++c2)
                bfr[c2] = *(const bf16x8*)&sB[wco + c2 * 16 + (lane & 15)][ks + (lane >> 4) * 8];
            #pragma unroll
            for (int r = 0; r < 4; ++r) {
                #pragma unroll
                for (int c2 = 0; c2 < 4; ++c2)
                    acc[r][c2] = __builtin_amdgcn_mfma_f32_16x16x32_bf16(af[r], bfr[c2], acc[r][c2], 0, 0, 0);
            }
        }
    }

    float* cb = cov + (size_t)cls * MSZ;
    int prow = ti * 128 + wro + ((lane >> 4) << 2);
    int pcol = tj * 128 + wco + (lane & 15);
    #pragma unroll
    for (int r = 0; r < 4; ++r) {
        #pragma unroll
        for (int c2 = 0; c2 < 4; ++c2) {
            #pragma unroll
            for (int v = 0; v < 4; ++v)
                atomicAdd(&cb[(size_t)(prow + r * 16 + v) * N_COLS + pcol + c2 * 16], acc[r][c2][v]);
        }
    }
}

// ---------------- prep: E_b = M_b/c_b - I in bf16 (full, mirrored) ----------------
// c_b = tr(M_b)/256 = 1 + scal*tr(cov_b)/256  =>  E = (scal/c)*cov + (1/c - 1)*I
__global__ __launch_bounds__(256) void prep_kernel(const float* __restrict__ cov,
                                                   const int* __restrict__ meta,
                                                   unsigned short* __restrict__ slab,
                                                   float* __restrict__ cvals) {
    int b = blockIdx.x;   // 0..10
    int t = threadIdx.x;
    float scal;
    if (b < NCLASS) scal = (float)N_COLS / (((float)meta[32 + b] + 1e-8f) * 0.01f);
    else            scal = (float)N_COLS / ((float)N_ROWS * 0.01f);

    __shared__ float red[256];
    float dsum;
    if (b < NCLASS) dsum = cov[(size_t)b * MSZ + t * 257];
    else {
        dsum = 0.f;
        #pragma unroll
        for (int cl = 0; cl < NCLASS; ++cl) dsum += cov[(size_t)cl * MSZ + t * 257];
    }
    red[t] = dsum;
    __syncthreads();
    for (int s = 128; s > 0; s >>= 1) {
        if (t < s) red[t] += red[t + s];
        __syncthreads();
    }
    float c = 1.f + scal * red[0] / 256.f;
    if (t == 0) cvals[b] = c;
    float es = scal / c;
    float dadd = 1.f / c - 1.f;

    unsigned short* Eb = slab + (size_t)b * MSZ;
    int r0 = t >> 5, cg = (t & 31) * 8;
    for (int ii = 0; ii < 32; ++ii) {
        int i = r0 + ii * 8;
        bool mb = (i >> 7) > (cg >> 7);      // cov stores upper 128-blocks; mirror (1,0)
        float v[8];
        if (!mb) {
            size_t off = (size_t)i * N_COLS + cg;
            if (b < NCLASS) {
                float4 a = *(const float4*)(cov + (size_t)b * MSZ + off);
                float4 bq = *(const float4*)(cov + (size_t)b * MSZ + off + 4);
                v[0] = a.x; v[1] = a.y; v[2] = a.z; v[3] = a.w;
                v[4] = bq.x; v[5] = bq.y; v[6] = bq.z; v[7] = bq.w;
            } else {
                #pragma unroll
                for (int jj = 0; jj < 8; ++jj) v[jj] = 0.f;
                #pragma unroll
                for (int cl = 0; cl < NCLASS; ++cl) {
                    float4 a = *(const float4*)(cov + (size_t)cl * MSZ + off);
                    float4 bq = *(const float4*)(cov + (size_t)cl * MSZ + off + 4);
                    v[0] += a.x; v[1] += a.y; v[2] += a.z; v[3] += a.w;
                    v[4] += bq.x; v[5] += bq.y; v[6] += bq.z; v[7] += bq.w;
                }
            }
        } else {
            #pragma unroll
            for (int jj = 0; jj < 8; ++jj) {
                size_t off = (size_t)(cg + jj) * N_COLS + i;
                float s;
                if (b < NCLASS) s = cov[(size_t)b * MSZ + off];
                else {
                    s = 0.f;
                    #pragma unroll
                    for (int cl = 0; cl < NCLASS; ++cl) s += cov[(size_t)cl * MSZ + off];
                }
                v[jj] = s;
            }
        }
        unsigned short o[8];
        #pragma unroll
        for (int jj = 0; jj < 8; ++jj)
            o[jj] = f2bf(es * v[jj] + ((cg + jj) == i ? dadd : 0.f));
        uint4 pk;
        pk.x = (unsigned)o[0] | ((unsigned)o[1] << 16);
        pk.y = (unsigned)o[2] | ((unsigned)o[3] << 16);
        pk.z = (unsigned)o[4] | ((unsigned)o[5] << 16);
        pk.w = (unsigned)o[6] | ((unsigned)o[7] << 16);
        *(uint4*)&Eb[(size_t)i * N_COLS + cg] = pk;
    }
}

// ---------------- mm_stage: D = A*B for symmetric bf16 256x256 (MFMA) ----------------
// grid (4 tiles, 11 matrices, z); z selects (ai,bi,di) pair for fused stages.
__global__ __launch_bounds__(256) void mm_stage(unsigned short* __restrict__ slab,
                                                int ai0, int bi0, int di0,
                                                int ai1, int bi1, int di1) {
    int z = blockIdx.z;
    int ai = z ? ai1 : ai0, bi = z ? bi1 : bi0, di = z ? di1 : di0;
    int m = blockIdx.y;
    int tile = blockIdx.x;
    int ti = tile >> 1, tj = tile & 1;
    const unsigned short* A = slab + ((size_t)ai * 11 + m) * MSZ;
    const unsigned short* B = slab + ((size_t)bi * 11 + m) * MSZ;
    unsigned short* D = slab + ((size_t)di * 11 + m) * MSZ;

    __shared__ unsigned short sA[128][72];
    __shared__ unsigned short sB[128][72];
    int t = threadIdx.x;
    int lane = t & 63, wave = t >> 6;
    int wro = (wave >> 1) * 64, wco = (wave & 1) * 64;

    f32x4 acc[4][4] = {};
    int sr = t >> 1;
    int sq = (t & 1) * 32;

    for (int ch = 0; ch < 4; ++ch) {
        int k0 = ch * 64;
        const uint4* ga = (const uint4*)(A + (size_t)(ti * 128 + sr) * N_COLS + k0 + sq);
        const uint4* gb = (const uint4*)(B + (size_t)(tj * 128 + sr) * N_COLS + k0 + sq);
        uint4 a0 = ga[0], a1 = ga[1], a2 = ga[2], a3 = ga[3];
        uint4 b0 = gb[0], b1 = gb[1], b2 = gb[2], b3 = gb[3];
        __syncthreads();
        *(uint4*)&sA[sr][sq]      = a0;
        *(uint4*)&sA[sr][sq + 8]  = a1;
        *(uint4*)&sA[sr][sq + 16] = a2;
        *(uint4*)&sA[sr][sq + 24] = a3;
        *(uint4*)&sB[sr][sq]      = b0;
        *(uint4*)&sB[sr][sq + 8]  = b1;
        *(uint4*)&sB[sr][sq + 16] = b2;
        *(uint4*)&sB[sr][sq + 24] = b3;
        __syncthreads();
        #pragma unroll
        for (int ks = 0; ks < 64; ks += 32) {
            bf16x8 af[4], bfr[4];
            #pragma unroll
            for (int r = 0; r < 4; ++r)
                af[r] = *(const bf16x8*)&sA[wro + r * 16 + (lane & 15)][ks + (lane >> 4) * 8];
            #pragma unroll
            for (int c2 = 0; c2 < 4; ++c2)
                bfr[c2] = *(const bf16x8*)&sB[wco + c2 * 16 + (lane & 15)][ks + (lane >> 4) * 8];
            #pragma unroll
            for (int r = 0; r < 4; ++r) {
                #pragma unroll
                for (int c2 = 0; c2 < 4; ++c2)
                    acc[r][c2] = __builtin_amdgcn_mfma_f32_16x16x32_bf16(af[r], bfr[c2], acc[r][c2], 0, 0, 0);
            }
        }
    }

    int prow = ti * 128 + wro + ((lane >> 4) << 2);
    int pcol = tj * 128 + wco + (lane & 15);
    #pragma unroll
    for (int r = 0; r < 4; ++r) {
        #pragma unroll
        for (int c2 = 0; c2 < 4; ++c2) {
            #pragma unroll
            for (int v = 0; v < 4; ++v)
                D[(size_t)(prow + r * 16 + v) * N_COLS + pcol + c2 * 16] = f2bf(acc[r][c2][v]);
        }
    }
}

// ---------------- trace: Frobenius pairings -> tr(E^k), k=1..10 ----------------
// traces[m*16 + v]: v=0:tr2 1:tr3 2:tr4 3:tr5 4:tr6 5:tr7 6:tr8 7:tr9 8:tr10 9:tr1
__global__ __launch_bounds__(256) void trace_kernel(const unsigned short* __restrict__ slab,
                                                    float* __restrict__ traces) {
    int m = blockIdx.x, t = threadIdx.x;
    const unsigned short* E = slab + (size_t)m * MSZ;
    const unsigned short* G = E + (size_t)11 * MSZ;
    const unsigned short* H = E + (size_t)22 * MSZ;
    const unsigned short* K = E + (size_t)33 * MSZ;
    const unsigned short* P = E + (size_t)44 * MSZ;

    float a0 = 0, a1 = 0, a2 = 0, a3 = 0, a4 = 0, a5 = 0, a6 = 0, a7 = 0, a8 = 0;
    float t1 = bf2f(E[(size_t)t * 257]);
    size_t rb = (size_t)t * N_COLS;
    for (int cg = 0; cg < 256; cg += 8) {
        float e[8], g[8], h[8], k[8], p[8];
        unpack8(E + rb + cg, e);
        unpack8(G + rb + cg, g);
        unpack8(H + rb + cg, h);
        unpack8(K + rb + cg, k);
        unpack8(P + rb + cg, p);
        #pragma unroll
        for (int j = 0; j < 8; ++j) {
            a0 = fmaf(e[j], e[j], a0);   // tr2
            a1 = fmaf(e[j], g[j], a1);   // tr3
            a2 = fmaf(g[j], g[j], a2);   // tr4
            a3 = fmaf(g[j], h[j], a3);   // tr5
            a4 = fmaf(h[j], h[j], a4);   // tr6
            a5 = fmaf(h[j], k[j], a5);   // tr7
            a6 = fmaf(k[j], k[j], a6);   // tr8
            a7 = fmaf(h[j], p[j], a7);   // tr9
            a8 = fmaf(k[j], p[j], a8);   // tr10
        }
    }
    float vals[10] = {a0, a1, a2, a3, a4, a5, a6, a7, a8, t1};
    __shared__ float red[256];
    for (int v = 0; v < 10; ++v) {
        red[t] = vals[v];
        __syncthreads();
        for (int s = 128; s > 0; s >>= 1) {
            if (t < s) red[t] += red[t + s];
            __syncthreads();
        }
        if (t == 0) traces[m * 16 + v] = red[0];
        __syncthreads();
    }
}

// ---------------- finalize ----------------
__global__ void finalize_kernel(const float* __restrict__ traces,
                                const float* __restrict__ cvals,
                                const int* __restrict__ meta,
                                float* __restrict__ out) {
    if (threadIdx.x == 0 && blockIdx.x == 0) {
        float logdet[11];
        for (int m = 0; m < 11; ++m) {
            const float* tr = traces + m * 16;
            // log(1+x) = x - x^2/2 + x^3/3 - ...
            logdet[m] = 256.f * __logf(cvals[m])
                      + tr[9]            // tr1
                      - tr[0] / 2.f + tr[1] / 3.f - tr[2] / 4.f + tr[3] / 5.f
                      - tr[4] / 6.f + tr[5] / 7.f - tr[6] / 8.f + tr[7] / 9.f
                      - tr[8] / 10.f;
        }
        float discrimn = 0.5f * logdet[NCLASS];       // GAM1 == 1 => empi == theo
        float compress = 0.f;
        for (int k = 0; k < NCLASS; ++k) {
            float trp = (float)meta[32 + k] + 1e-8f;
            compress += logdet[k] * trp;
        }
        compress = compress / (float)N_ROWS * 0.5f;
        out[0] = -discrimn + compress;                // GAM2 == 1
        out[1] = discrimn;
        out[2] = compress;
        out[3] = discrimn;
        out[4] = compress;
    }
}

extern "C" void kernel_launch(void* const* d_in, const int* in_sizes, int n_in,
                              void* d_out, int out_size, void* d_ws, size_t ws_size,
                              hipStream_t stream) {
    const float* X = (const float*)d_in[0];
    const int*   Y = (const int*)d_in[1];
    float* out = (float*)d_out;

    char* ws = (char*)d_ws;
    const size_t o_cov   = 0;                        // 10*256*256*4 = 2,621,440
    const size_t o_meta  = 2621440;                  // 64 ints
    const size_t o_blkc  = o_meta + 256;             // 2560 ints
    const size_t o_blkb  = o_blkc + 10240;           // 2560 ints
    const size_t o_order = o_blkb + 10240;           // 65536 ints
    const size_t o_small = o_order + 262144;         // cvals (11 f) + traces (176 f)
    const size_t o_xst   = o_small + 1024;           // 256*XP*2 = 33,882,112

    float*          cov      = (float*)(ws + o_cov);
    int*            meta     = (int*)(ws + o_meta);
    int*            blk_cnt  = (int*)(ws + o_blkc);
    int*            blk_base = (int*)(ws + o_blkb);
    int*            order    = (int*)(ws + o_order);
    float*          cvals    = (float*)(ws + o_small);
    float*          traces   = (float*)(ws + o_small + 64);
    unsigned short* Xst      = (unsigned short*)(ws + o_xst);
    unsigned short* slab     = Xst;                  // E/G/H/K/P overlay Xst after cov

    hipMemsetAsync(cov, 0, (size_t)NCLASS * MSZ * sizeof(float), stream);
    hipLaunchKernelGGL(blkhist_kernel, dim3(256), dim3(256), 0, stream, Y, blk_cnt);
    hipLaunchKernelGGL(scan_kernel, dim3(1), dim3(1024), 0, stream, blk_cnt, meta, blk_base);
    hipLaunchKernelGGL(order_kernel, dim3(256), dim3(256), 0, stream, Y, blk_base, order);
    hipLaunchKernelGGL(gather_kernel, dim3(XP / 64), dim3(256), 0, stream, X, order, meta, Xst);
    hipLaunchKernelGGL(cov_mfma, dim3(3, NCLASS, SPL), dim3(256), 0, stream, Xst, meta, cov);
    hipLaunchKernelGGL(prep_kernel, dim3(11), dim3(256), 0, stream, cov, meta, slab, cvals);
    // S1: G = E*E
    hipLaunchKernelGGL(mm_stage, dim3(4, 11, 1), dim3(256), 0, stream, slab, 0, 0, 1, 0, 0, 1);
    // S2: H = E*G ; K = G*G
    hipLaunchKernelGGL(mm_stage, dim3(4, 11, 2), dim3(256), 0, stream, slab, 0, 1, 2, 1, 1, 3);
    // S3: P = H*H
    hipLaunchKernelGGL(mm_stage, dim3(4, 11, 1), dim3(256), 0, stream, slab, 2, 2, 4, 2, 2, 4);
    hipLaunchKernelGGL(trace_kernel, dim3(11), dim3(256), 0, stream, slab, traces);
    hipLaunchKernelGGL(finalize_kernel, dim3(1), dim3(64), 0, stream, traces, cvals, meta, out);
}

// Round 6
// 217.302 us; speedup vs baseline: 9.2012x; 1.5095x over previous
//
#include <hip/hip_runtime.h>

#define N_ROWS 65536
#define N_COLS 256
#define NCLASS 10
#define XP 66176            // Xst col pitch: 65536 + 10*64 pad
#define SPL 16              // K-splits per (class,tile)
#define MSZ 65536           // 256*256 elements per matrix

typedef __attribute__((ext_vector_type(8))) short bf16x8;
typedef __attribute__((ext_vector_type(4))) float f32x4;

// meta layout (ints): [0..10] off_pad, [16..26] offsets (unpadded), [32..41] counts
// slab layout (bf16): s*11*MSZ + m*MSZ for s in {0:E,1:G=E^2,2:H=E^3,3:K=E^4,4:P=E^6}

static __device__ __forceinline__ unsigned short f2bf(float f) {
    unsigned int u = __float_as_uint(f);
    unsigned int r = (u + 0x7FFFu + ((u >> 16) & 1u)) >> 16;   // RTN-even
    return (unsigned short)r;
}
static __device__ __forceinline__ float bf2f(unsigned short s) {
    return __uint_as_float(((unsigned int)s) << 16);
}
static __device__ __forceinline__ void unpack8(const unsigned short* p, float* f) {
    uint4 u = *(const uint4*)p;
    f[0] = __uint_as_float(u.x << 16); f[1] = __uint_as_float(u.x & 0xffff0000u);
    f[2] = __uint_as_float(u.y << 16); f[3] = __uint_as_float(u.y & 0xffff0000u);
    f[4] = __uint_as_float(u.z << 16); f[5] = __uint_as_float(u.z & 0xffff0000u);
    f[6] = __uint_as_float(u.w << 16); f[7] = __uint_as_float(u.w & 0xffff0000u);
}
static __device__ __forceinline__ float scal_of(int b, const int* meta) {
    if (b < NCLASS) return (float)N_COLS / (((float)meta[32 + b] + 1e-8f) * 0.01f);
    return (float)N_COLS / ((float)N_ROWS * 0.01f);
}

// ---------------- Phase A: per-block class histogram ----------------
__global__ __launch_bounds__(256) void blkhist_kernel(const int* __restrict__ Y,
                                                      int* __restrict__ blk_cnt) {
    __shared__ int h[NCLASS];
    int b = blockIdx.x, t = threadIdx.x;
    if (t < NCLASS) h[t] = 0;
    __syncthreads();
    atomicAdd(&h[Y[b * 256 + t]], 1);
    __syncthreads();
    if (t < NCLASS) blk_cnt[b * NCLASS + t] = h[t];
}

// ---------------- Phase B: scan (wave-per-class shuffle scans) ----------------
__global__ __launch_bounds__(1024) void scan_kernel(const int* __restrict__ blk_cnt,
                                                    int* __restrict__ meta,
                                                    int* __restrict__ blk_base) {
    int t = threadIdx.x;
    int w = t >> 6, l = t & 63;
    __shared__ int tots[16];
    __shared__ int soff_s[16];
    int s0 = 0, s1 = 0, s2 = 0, s3 = 0;
    if (w < NCLASS) {
        s0 = blk_cnt[(l      ) * NCLASS + w];
        s1 = blk_cnt[(l +  64) * NCLASS + w];
        s2 = blk_cnt[(l + 128) * NCLASS + w];
        s3 = blk_cnt[(l + 192) * NCLASS + w];
    }
    int x0 = s0, x1 = s1, x2 = s2, x3 = s3;
    for (int d = 1; d < 64; d <<= 1) {
        int y0 = __shfl_up(x0, d, 64), y1 = __shfl_up(x1, d, 64);
        int y2 = __shfl_up(x2, d, 64), y3 = __shfl_up(x3, d, 64);
        if (l >= d) { x0 += y0; x1 += y1; x2 += y2; x3 += y3; }
    }
    int T0 = __shfl(x0, 63, 64), T1 = __shfl(x1, 63, 64);
    int T2 = __shfl(x2, 63, 64), T3 = __shfl(x3, 63, 64);
    if (w < NCLASS && l == 63) tots[w] = T0 + T1 + T2 + T3;
    __syncthreads();
    if (t == 0) {
        int off = 0, offp = 0;
        for (int c = 0; c < NCLASS; ++c) {
            soff_s[c] = off;
            meta[16 + c] = off;
            meta[c] = offp;
            meta[32 + c] = tots[c];
            off += tots[c];
            offp += (tots[c] + 63) & ~63;
        }
        meta[16 + NCLASS] = off;
        meta[NCLASS] = offp;
    }
    __syncthreads();
    if (w < NCLASS) {
        int base = soff_s[w];
        blk_base[(l      ) * NCLASS + w] = base + x0 - s0;
        blk_base[(l +  64) * NCLASS + w] = base + T0 + x1 - s1;
        blk_base[(l + 128) * NCLASS + w] = base + T0 + T1 + x2 - s2;
        blk_base[(l + 192) * NCLASS + w] = base + T0 + T1 + T2 + x3 - s3;
    }
}

// ---------------- Phase C: build sorted order ----------------
__global__ __launch_bounds__(256) void order_kernel(const int* __restrict__ Y,
                                                    const int* __restrict__ blk_base,
                                                    int* __restrict__ order) {
    __shared__ int lcur[NCLASS];
    int b = blockIdx.x, t = threadIdx.x;
    if (t < NCLASS) lcur[t] = 0;
    __syncthreads();
    int i = b * 256 + t;
    int y = Y[i];
    int pos = blk_base[b * NCLASS + y] + atomicAdd(&lcur[y], 1);
    order[pos] = i;
}

// ---------------- Phase D: gather + fp32->bf16 + transpose ----------------
__global__ __launch_bounds__(256) void gather_kernel(const float* __restrict__ X,
                                                     const int* __restrict__ order,
                                                     const int* __restrict__ meta,
                                                     unsigned short* __restrict__ Xst) {
    __shared__ unsigned short sT[256 * 72];   // pitch 72 shorts = 144B (16B-aligned rows)
    int p0 = blockIdx.x * 64;
    if (p0 >= meta[NCLASS]) return;
    int cls = 0;
    while (p0 >= meta[cls + 1]) ++cls;       // 64-tiles never straddle classes
    int lp0 = p0 - meta[cls];
    int cnt = meta[32 + cls];
    int obase = meta[16 + cls];

    int t = threadIdx.x;
    int p = t >> 2;                 // 0..63 local pos
    int cseg = (t & 3) * 64;        // feature segment
    int lp = lp0 + p;
    int row = (lp < cnt) ? order[obase + lp] : -1;
    const float* xr = X + (size_t)(row < 0 ? 0 : row) * N_COLS;
    #pragma unroll
    for (int k = 0; k < 16; ++k) {
        int col = cseg + k * 4;
        float4 v;
        if (row >= 0) v = *(const float4*)(xr + col);
        else          v = make_float4(0.f, 0.f, 0.f, 0.f);
        sT[(col + 0) * 72 + p] = f2bf(v.x);
        sT[(col + 1) * 72 + p] = f2bf(v.y);
        sT[(col + 2) * 72 + p] = f2bf(v.z);
        sT[(col + 3) * 72 + p] = f2bf(v.w);
    }
    __syncthreads();
    int pc = t & 7;          // pos-chunk 0..7 (8 shorts each)
    int cb = t >> 3;         // col base 0..31
    #pragma unroll
    for (int j = 0; j < 8; ++j) {
        int col = cb + j * 32;
        uint4 v = *(const uint4*)&sT[col * 72 + pc * 8];
        *(uint4*)(Xst + (size_t)col * XP + p0 + pc * 8) = v;
    }
}

// ---------------- cov via bf16 MFMA syrk ----------------
__global__ __launch_bounds__(256) void cov_mfma(const unsigned short* __restrict__ Xst,
                                                const int* __restrict__ meta,
                                                float* __restrict__ cov) {
    __shared__ unsigned short sA[128][72];
    __shared__ unsigned short sB[128][72];
    int cls = blockIdx.y;
    int tile = blockIdx.x;
    int ti = (tile == 2) ? 1 : 0;
    int tj = (tile == 0) ? 0 : 1;
    int kb = meta[cls];
    int len = meta[cls + 1] - kb;
    int nch = len >> 6;
    int s = blockIdx.z;
    int ch0 = (nch * s) / SPL, ch1 = (nch * (s + 1)) / SPL;
    if (ch0 >= ch1) return;

    int t = threadIdx.x;
    int lane = t & 63, wave = t >> 6;
    int wro = (wave >> 1) * 64, wco = (wave & 1) * 64;

    f32x4 acc[4][4] = {};

    int sr = t >> 1;
    int sq = (t & 1) * 32;

    for (int ch = ch0; ch < ch1; ++ch) {
        int k0 = kb + ch * 64;
        const uint4* ga = (const uint4*)(Xst + (size_t)(ti * 128 + sr) * XP + k0 + sq);
        const uint4* gb = (const uint4*)(Xst + (size_t)(tj * 128 + sr) * XP + k0 + sq);
        uint4 a0 = ga[0], a1 = ga[1], a2 = ga[2], a3 = ga[3];
        uint4 b0 = gb[0], b1 = gb[1], b2 = gb[2], b3 = gb[3];
        __syncthreads();
        *(uint4*)&sA[sr][sq]      = a0;
        *(uint4*)&sA[sr][sq + 8]  = a1;
        *(uint4*)&sA[sr][sq + 16] = a2;
        *(uint4*)&sA[sr][sq + 24] = a3;
        *(uint4*)&sB[sr][sq]      = b0;
        *(uint4*)&sB[sr][sq + 8]  = b1;
        *(uint4*)&sB[sr][sq + 16] = b2;
        *(uint4*)&sB[sr][sq + 24] = b3;
        __syncthreads();
        #pragma unroll
        for (int ks = 0; ks < 64; ks += 32) {
            bf16x8 af[4], bfr[4];
            #pragma unroll
            for (int r = 0; r < 4; ++r)
                af[r] = *(const bf16x8*)&sA[wro + r * 16 + (lane & 15)][ks + (lane >> 4) * 8];
            #pragma unroll
            for (int c2 = 0; c2 < 4; ++c2)
                bfr[c2] = *(const bf16x8*)&sB[wco + c2 * 16 + (lane & 15)][ks + (lane >> 4) * 8];
            #pragma unroll
            for (int r = 0; r < 4; ++r) {
                #pragma unroll
                for (int c2 = 0; c2 < 4; ++c2)
                    acc[r][c2] = __builtin_amdgcn_mfma_f32_16x16x32_bf16(af[r], bfr[c2], acc[r][c2], 0, 0, 0);
            }
        }
    }

    float* cb = cov + (size_t)cls * MSZ;
    int prow = ti * 128 + wro + ((lane >> 4) << 2);
    int pcol = tj * 128 + wco + (lane & 15);
    #pragma unroll
    for (int r = 0; r < 4; ++r) {
        #pragma unroll
        for (int c2 = 0; c2 < 4; ++c2) {
            #pragma unroll
            for (int v = 0; v < 4; ++v)
                atomicAdd(&cb[(size_t)(prow + r * 16 + v) * N_COLS + pcol + c2 * 16], acc[r][c2][v]);
        }
    }
}

// ---------------- cvals: c_b = 1 + scal*tr(cov_b)/256 ----------------
__global__ __launch_bounds__(256) void cvals_kernel(const float* __restrict__ cov,
                                                    const int* __restrict__ meta,
                                                    float* __restrict__ cvals) {
    int b = blockIdx.x, t = threadIdx.x;
    float dsum;
    if (b < NCLASS) dsum = cov[(size_t)b * MSZ + t * 257];
    else {
        dsum = 0.f;
        #pragma unroll
        for (int cl = 0; cl < NCLASS; ++cl) dsum += cov[(size_t)cl * MSZ + t * 257];
    }
    __shared__ float red[256];
    red[t] = dsum;
    __syncthreads();
    for (int s = 128; s > 0; s >>= 1) {
        if (t < s) red[t] += red[t + s];
        __syncthreads();
    }
    if (t == 0) cvals[b] = 1.f + scal_of(b, meta) * red[0] / 256.f;
}

// ---------------- prep: E_b = M_b/c_b - I in bf16; grid (11, 32) ----------------
__global__ __launch_bounds__(256) void prep_kernel(const float* __restrict__ cov,
                                                   const int* __restrict__ meta,
                                                   const float* __restrict__ cvals,
                                                   unsigned short* __restrict__ slab) {
    int b = blockIdx.x;   // matrix 0..10
    int t = threadIdx.x;
    float c = cvals[b];
    float es = scal_of(b, meta) / c;
    float dadd = 1.f / c - 1.f;

    int i  = blockIdx.y * 8 + (t >> 5);   // row
    int cg = (t & 31) * 8;                // col group (8 elems)
    bool mb = (i >> 7) > (cg >> 7);       // cov stores upper 128-blocks; mirror (1,0)
    float v[8];
    if (!mb) {
        size_t off = (size_t)i * N_COLS + cg;
        if (b < NCLASS) {
            float4 a = *(const float4*)(cov + (size_t)b * MSZ + off);
            float4 bq = *(const float4*)(cov + (size_t)b * MSZ + off + 4);
            v[0] = a.x; v[1] = a.y; v[2] = a.z; v[3] = a.w;
            v[4] = bq.x; v[5] = bq.y; v[6] = bq.z; v[7] = bq.w;
        } else {
            #pragma unroll
            for (int jj = 0; jj < 8; ++jj) v[jj] = 0.f;
            #pragma unroll
            for (int cl = 0; cl < NCLASS; ++cl) {
                float4 a = *(const float4*)(cov + (size_t)cl * MSZ + off);
                float4 bq = *(const float4*)(cov + (size_t)cl * MSZ + off + 4);
                v[0] += a.x; v[1] += a.y; v[2] += a.z; v[3] += a.w;
                v[4] += bq.x; v[5] += bq.y; v[6] += bq.z; v[7] += bq.w;
            }
        }
    } else {
        #pragma unroll
        for (int jj = 0; jj < 8; ++jj) {
            size_t off = (size_t)(cg + jj) * N_COLS + i;
            float s;
            if (b < NCLASS) s = cov[(size_t)b * MSZ + off];
            else {
                s = 0.f;
                #pragma unroll
                for (int cl = 0; cl < NCLASS; ++cl) s += cov[(size_t)cl * MSZ + off];
            }
            v[jj] = s;
        }
    }
    unsigned short o[8];
    #pragma unroll
    for (int jj = 0; jj < 8; ++jj)
        o[jj] = f2bf(es * v[jj] + ((cg + jj) == i ? dadd : 0.f));
    uint4 pk;
    pk.x = (unsigned)o[0] | ((unsigned)o[1] << 16);
    pk.y = (unsigned)o[2] | ((unsigned)o[3] << 16);
    pk.z = (unsigned)o[4] | ((unsigned)o[5] << 16);
    pk.w = (unsigned)o[6] | ((unsigned)o[7] << 16);
    *(uint4*)&slab[(size_t)b * MSZ + (size_t)i * N_COLS + cg] = pk;
}

// ---------------- mm_stage: D = A*B for symmetric bf16 256x256 (MFMA) ----------------
__global__ __launch_bounds__(256) void mm_stage(unsigned short* __restrict__ slab,
                                                int ai0, int bi0, int di0,
                                                int ai1, int bi1, int di1) {
    int z = blockIdx.z;
    int ai = z ? ai1 : ai0, bi = z ? bi1 : bi0, di = z ? di1 : di0;
    int m = blockIdx.y;
    int tile = blockIdx.x;
    int ti = tile >> 1, tj = tile & 1;
    const unsigned short* A = slab + ((size_t)ai * 11 + m) * MSZ;
    const unsigned short* B = slab + ((size_t)bi * 11 + m) * MSZ;
    unsigned short* D = slab + ((size_t)di * 11 + m) * MSZ;

    __shared__ unsigned short sA[128][72];
    __shared__ unsigned short sB[128][72];
    int t = threadIdx.x;
    int lane = t & 63, wave = t >> 6;
    int wro = (wave >> 1) * 64, wco = (wave & 1) * 64;

    f32x4 acc[4][4] = {};
    int sr = t >> 1;
    int sq = (t & 1) * 32;

    for (int ch = 0; ch < 4; ++ch) {
        int k0 = ch * 64;
        const uint4* ga = (const uint4*)(A + (size_t)(ti * 128 + sr) * N_COLS + k0 + sq);
        const uint4* gb = (const uint4*)(B + (size_t)(tj * 128 + sr) * N_COLS + k0 + sq);
        uint4 a0 = ga[0], a1 = ga[1], a2 = ga[2], a3 = ga[3];
        uint4 b0 = gb[0], b1 = gb[1], b2 = gb[2], b3 = gb[3];
        __syncthreads();
        *(uint4*)&sA[sr][sq]      = a0;
        *(uint4*)&sA[sr][sq + 8]  = a1;
        *(uint4*)&sA[sr][sq + 16] = a2;
        *(uint4*)&sA[sr][sq + 24] = a3;
        *(uint4*)&sB[sr][sq]      = b0;
        *(uint4*)&sB[sr][sq + 8]  = b1;
        *(uint4*)&sB[sr][sq + 16] = b2;
        *(uint4*)&sB[sr][sq + 24] = b3;
        __syncthreads();
        #pragma unroll
        for (int ks = 0; ks < 64; ks += 32) {
            bf16x8 af[4], bfr[4];
            #pragma unroll
            for (int r = 0; r < 4; ++r)
                af[r] = *(const bf16x8*)&sA[wro + r * 16 + (lane & 15)][ks + (lane >> 4) * 8];
            #pragma unroll
            for (int c2 = 0; c2 < 4; ++c2)
                bfr[c2] = *(const bf16x8*)&sB[wco + c2 * 16 + (lane & 15)][ks + (lane >> 4) * 8];
            #pragma unroll
            for (int r = 0; r < 4; ++r) {
                #pragma unroll
                for (int c2 = 0; c2 < 4; ++c2)
                    acc[r][c2] = __builtin_amdgcn_mfma_f32_16x16x32_bf16(af[r], bfr[c2], acc[r][c2], 0, 0, 0);
            }
        }
    }

    int prow = ti * 128 + wro + ((lane >> 4) << 2);
    int pcol = tj * 128 + wco + (lane & 15);
    #pragma unroll
    for (int r = 0; r < 4; ++r) {
        #pragma unroll
        for (int c2 = 0; c2 < 4; ++c2) {
            #pragma unroll
            for (int v = 0; v < 4; ++v)
                D[(size_t)(prow + r * 16 + v) * N_COLS + pcol + c2 * 16] = f2bf(acc[r][c2][v]);
        }
    }
}

// ---------------- trace: Frobenius pairings -> tr(E^k); grid (11, 8) ----------------
// traces[m*16 + v]: v=0:tr2 1:tr3 2:tr4 3:tr5 4:tr6 5:tr7 6:tr8 7:tr9 8:tr10 9:tr1
__global__ __launch_bounds__(256) void trace_kernel(const unsigned short* __restrict__ slab,
                                                    float* __restrict__ traces) {
    int m = blockIdx.x, t = threadIdx.x;
    int r  = blockIdx.y * 32 + (t >> 3);   // row
    int cs = (t & 7) * 32;                 // col segment (32 elems)
    const unsigned short* E = slab + (size_t)m * MSZ;
    const unsigned short* G = E + (size_t)11 * MSZ;
    const unsigned short* H = E + (size_t)22 * MSZ;
    const unsigned short* K = E + (size_t)33 * MSZ;
    const unsigned short* P = E + (size_t)44 * MSZ;

    float a0 = 0, a1 = 0, a2 = 0, a3 = 0, a4 = 0, a5 = 0, a6 = 0, a7 = 0, a8 = 0;
    float t1 = (r >= cs && r < cs + 32) ? bf2f(E[(size_t)r * 257]) : 0.f;
    size_t rb = (size_t)r * N_COLS + cs;
    #pragma unroll
    for (int cg = 0; cg < 32; cg += 8) {
        float e[8], g[8], h[8], k[8], p[8];
        unpack8(E + rb + cg, e);
        unpack8(G + rb + cg, g);
        unpack8(H + rb + cg, h);
        unpack8(K + rb + cg, k);
        unpack8(P + rb + cg, p);
        #pragma unroll
        for (int j = 0; j < 8; ++j) {
            a0 = fmaf(e[j], e[j], a0);   // tr2
            a1 = fmaf(e[j], g[j], a1);   // tr3
            a2 = fmaf(g[j], g[j], a2);   // tr4
            a3 = fmaf(g[j], h[j], a3);   // tr5
            a4 = fmaf(h[j], h[j], a4);   // tr6
            a5 = fmaf(h[j], k[j], a5);   // tr7
            a6 = fmaf(k[j], k[j], a6);   // tr8
            a7 = fmaf(h[j], p[j], a7);   // tr9
            a8 = fmaf(k[j], p[j], a8);   // tr10
        }
    }
    float vals[10] = {a0, a1, a2, a3, a4, a5, a6, a7, a8, t1};
    #pragma unroll
    for (int v = 0; v < 10; ++v) {
        float x = vals[v];
        #pragma unroll
        for (int d = 32; d > 0; d >>= 1) x += __shfl_down(x, d, 64);
        if ((t & 63) == 0) atomicAdd(&traces[m * 16 + v], x);
    }
}

// ---------------- finalize ----------------
__global__ void finalize_kernel(const float* __restrict__ traces,
                                const float* __restrict__ cvals,
                                const int* __restrict__ meta,
                                float* __restrict__ out) {
    if (threadIdx.x == 0 && blockIdx.x == 0) {
        float logdet[11];
        for (int m = 0; m < 11; ++m) {
            const float* tr = traces + m * 16;
            logdet[m] = 256.f * __logf(cvals[m])
                      + tr[9]
                      - tr[0] / 2.f + tr[1] / 3.f - tr[2] / 4.f + tr[3] / 5.f
                      - tr[4] / 6.f + tr[5] / 7.f - tr[6] / 8.f + tr[7] / 9.f
                      - tr[8] / 10.f;
        }
        float discrimn = 0.5f * logdet[NCLASS];       // GAM1 == 1 => empi == theo
        float compress = 0.f;
        for (int k = 0; k < NCLASS; ++k) {
            float trp = (float)meta[32 + k] + 1e-8f;
            compress += logdet[k] * trp;
        }
        compress = compress / (float)N_ROWS * 0.5f;
        out[0] = -discrimn + compress;                // GAM2 == 1
        out[1] = discrimn;
        out[2] = compress;
        out[3] = discrimn;
        out[4] = compress;
    }
}

extern "C" void kernel_launch(void* const* d_in, const int* in_sizes, int n_in,
                              void* d_out, int out_size, void* d_ws, size_t ws_size,
                              hipStream_t stream) {
    const float* X = (const float*)d_in[0];
    const int*   Y = (const int*)d_in[1];
    float* out = (float*)d_out;

    char* ws = (char*)d_ws;
    const size_t o_cov   = 0;                        // 10*256*256*4 = 2,621,440
    const size_t o_meta  = 2621440;                  // 64 ints
    const size_t o_blkc  = o_meta + 256;             // 2560 ints
    const size_t o_blkb  = o_blkc + 10240;           // 2560 ints
    const size_t o_order = o_blkb + 10240;           // 65536 ints
    const size_t o_small = o_order + 262144;         // cvals (16 f) + traces (176 f)
    const size_t o_xst   = o_small + 1024;           // 256*XP*2 = 33,882,112

    float*          cov      = (float*)(ws + o_cov);
    int*            meta     = (int*)(ws + o_meta);
    int*            blk_cnt  = (int*)(ws + o_blkc);
    int*            blk_base = (int*)(ws + o_blkb);
    int*            order    = (int*)(ws + o_order);
    float*          cvals    = (float*)(ws + o_small);
    float*          traces   = (float*)(ws + o_small + 64);
    unsigned short* Xst      = (unsigned short*)(ws + o_xst);
    unsigned short* slab     = Xst;                  // E/G/H/K/P overlay Xst after cov

    hipMemsetAsync(cov, 0, (size_t)NCLASS * MSZ * sizeof(float), stream);
    hipMemsetAsync(ws + o_small, 0, 1024, stream);   // zero cvals+traces (atomic targets)
    hipLaunchKernelGGL(blkhist_kernel, dim3(256), dim3(256), 0, stream, Y, blk_cnt);
    hipLaunchKernelGGL(scan_kernel, dim3(1), dim3(1024), 0, stream, blk_cnt, meta, blk_base);
    hipLaunchKernelGGL(order_kernel, dim3(256), dim3(256), 0, stream, Y, blk_base, order);
    hipLaunchKernelGGL(gather_kernel, dim3(XP / 64), dim3(256), 0, stream, X, order, meta, Xst);
    hipLaunchKernelGGL(cov_mfma, dim3(3, NCLASS, SPL), dim3(256), 0, stream, Xst, meta, cov);
    hipLaunchKernelGGL(cvals_kernel, dim3(11), dim3(256), 0, stream, cov, meta, cvals);
    hipLaunchKernelGGL(prep_kernel, dim3(11, 32), dim3(256), 0, stream, cov, meta, cvals, slab);
    // S1: G = E*E
    hipLaunchKernelGGL(mm_stage, dim3(4, 11, 1), dim3(256), 0, stream, slab, 0, 0, 1, 0, 0, 1);
    // S2: H = E*G ; K = G*G
    hipLaunchKernelGGL(mm_stage, dim3(4, 11, 2), dim3(256), 0, stream, slab, 0, 1, 2, 1, 1, 3);
    // S3: P = H*H
    hipLaunchKernelGGL(mm_stage, dim3(4, 11, 1), dim3(256), 0, stream, slab, 2, 2, 4, 2, 2, 4);
    hipLaunchKernelGGL(trace_kernel, dim3(11, 8), dim3(256), 0, stream, slab, traces);
    hipLaunchKernelGGL(finalize_kernel, dim3(1), dim3(64), 0, stream, traces, cvals, meta, out);
}

// Round 7
// 205.817 us; speedup vs baseline: 9.7147x; 1.0558x over previous
//
#include <hip/hip_runtime.h>

#define N_ROWS 65536
#define N_COLS 256
#define NCLASS 10
#define XP 66176            // Xst col pitch: 65536 + 10*64 pad
#define SPL 16              // K-splits per (class,tile)
#define MSZ 65536           // 256*256 elements per matrix

typedef __attribute__((ext_vector_type(8))) short bf16x8;
typedef __attribute__((ext_vector_type(4))) float f32x4;

// meta layout (ints): [0..10] off_pad, [16..26] offsets (unpadded), [32..41] counts
// slab layout (bf16): s*11*MSZ + m*MSZ for s in {0:E,1:G=E^2,2:H=E^3,3:K=E^4,4:P=E^6}

static __device__ __forceinline__ unsigned short f2bf(float f) {
    unsigned int u = __float_as_uint(f);
    unsigned int r = (u + 0x7FFFu + ((u >> 16) & 1u)) >> 16;   // RTN-even
    return (unsigned short)r;
}
static __device__ __forceinline__ float bf2f(unsigned short s) {
    return __uint_as_float(((unsigned int)s) << 16);
}
static __device__ __forceinline__ void unpack8(const unsigned short* p, float* f) {
    uint4 u = *(const uint4*)p;
    f[0] = __uint_as_float(u.x << 16); f[1] = __uint_as_float(u.x & 0xffff0000u);
    f[2] = __uint_as_float(u.y << 16); f[3] = __uint_as_float(u.y & 0xffff0000u);
    f[4] = __uint_as_float(u.z << 16); f[5] = __uint_as_float(u.z & 0xffff0000u);
    f[6] = __uint_as_float(u.w << 16); f[7] = __uint_as_float(u.w & 0xffff0000u);
}
static __device__ __forceinline__ float scal_of(int b, const int* meta) {
    if (b < NCLASS) return (float)N_COLS / (((float)meta[32 + b] + 1e-8f) * 0.01f);
    return (float)N_COLS / ((float)N_ROWS * 0.01f);
}

// ---------------- Phase A: per-block class histogram ----------------
__global__ __launch_bounds__(256) void blkhist_kernel(const int* __restrict__ Y,
                                                      int* __restrict__ blk_cnt) {
    __shared__ int h[NCLASS];
    int b = blockIdx.x, t = threadIdx.x;
    if (t < NCLASS) h[t] = 0;
    __syncthreads();
    atomicAdd(&h[Y[b * 256 + t]], 1);
    __syncthreads();
    if (t < NCLASS) blk_cnt[b * NCLASS + t] = h[t];
}

// ---------------- Phase B: scan (wave-per-class shuffle scans) ----------------
__global__ __launch_bounds__(1024) void scan_kernel(const int* __restrict__ blk_cnt,
                                                    int* __restrict__ meta,
                                                    int* __restrict__ blk_base) {
    int t = threadIdx.x;
    int w = t >> 6, l = t & 63;
    __shared__ int tots[16];
    __shared__ int soff_s[16];
    int s0 = 0, s1 = 0, s2 = 0, s3 = 0;
    if (w < NCLASS) {
        s0 = blk_cnt[(l      ) * NCLASS + w];
        s1 = blk_cnt[(l +  64) * NCLASS + w];
        s2 = blk_cnt[(l + 128) * NCLASS + w];
        s3 = blk_cnt[(l + 192) * NCLASS + w];
    }
    int x0 = s0, x1 = s1, x2 = s2, x3 = s3;
    for (int d = 1; d < 64; d <<= 1) {
        int y0 = __shfl_up(x0, d, 64), y1 = __shfl_up(x1, d, 64);
        int y2 = __shfl_up(x2, d, 64), y3 = __shfl_up(x3, d, 64);
        if (l >= d) { x0 += y0; x1 += y1; x2 += y2; x3 += y3; }
    }
    int T0 = __shfl(x0, 63, 64), T1 = __shfl(x1, 63, 64);
    int T2 = __shfl(x2, 63, 64), T3 = __shfl(x3, 63, 64);
    if (w < NCLASS && l == 63) tots[w] = T0 + T1 + T2 + T3;
    __syncthreads();
    if (t == 0) {
        int off = 0, offp = 0;
        for (int c = 0; c < NCLASS; ++c) {
            soff_s[c] = off;
            meta[16 + c] = off;
            meta[c] = offp;
            meta[32 + c] = tots[c];
            off += tots[c];
            offp += (tots[c] + 63) & ~63;
        }
        meta[16 + NCLASS] = off;
        meta[NCLASS] = offp;
    }
    __syncthreads();
    if (w < NCLASS) {
        int base = soff_s[w];
        blk_base[(l      ) * NCLASS + w] = base + x0 - s0;
        blk_base[(l +  64) * NCLASS + w] = base + T0 + x1 - s1;
        blk_base[(l + 128) * NCLASS + w] = base + T0 + T1 + x2 - s2;
        blk_base[(l + 192) * NCLASS + w] = base + T0 + T1 + T2 + x3 - s3;
    }
}

// ---------------- Phase C: build sorted order ----------------
__global__ __launch_bounds__(256) void order_kernel(const int* __restrict__ Y,
                                                    const int* __restrict__ blk_base,
                                                    int* __restrict__ order) {
    __shared__ int lcur[NCLASS];
    int b = blockIdx.x, t = threadIdx.x;
    if (t < NCLASS) lcur[t] = 0;
    __syncthreads();
    int i = b * 256 + t;
    int y = Y[i];
    int pos = blk_base[b * NCLASS + y] + atomicAdd(&lcur[y], 1);
    order[pos] = i;
}

// ---------------- Phase D: gather + fp32->bf16 + transpose ----------------
// Phase 1: each wave reads full 1KB rows (lane l -> float4 at col 4l), two rows
// per iteration packed into dwords (low short = even pos). LDS layout:
// sT32[col][slot], slot = (p2 + (col>>2)) & 31  => write banks (p2+l)%32 = 2-way.
// Phase 2: de-rotate with b32 reads, pack uint4, 128B-contiguous global stores.
__global__ __launch_bounds__(256) void gather_kernel(const float* __restrict__ X,
                                                     const int* __restrict__ order,
                                                     const int* __restrict__ meta,
                                                     unsigned short* __restrict__ Xst) {
    __shared__ unsigned int sT32[256 * 32];   // 32 KB
    int p0 = blockIdx.x * 64;
    if (p0 >= meta[NCLASS]) return;
    int cls = 0;
    while (p0 >= meta[cls + 1]) ++cls;       // 64-tiles never straddle classes
    int lp0 = p0 - meta[cls];
    int cnt = meta[32 + cls];
    int obase = meta[16 + cls];

    int t = threadIdx.x;
    int w = t >> 6, l = t & 63;

    #pragma unroll
    for (int rp = 0; rp < 8; ++rp) {
        int p2 = w * 8 + rp;                  // 0..31 (pos pair index)
        int lpa = lp0 + p2 * 2;
        int lpb = lpa + 1;
        int ra = (lpa < cnt) ? order[obase + lpa] : -1;   // wave-uniform
        int rb = (lpb < cnt) ? order[obase + lpb] : -1;
        float4 va = make_float4(0.f, 0.f, 0.f, 0.f);
        float4 vb = make_float4(0.f, 0.f, 0.f, 0.f);
        if (ra >= 0) va = *(const float4*)(X + (size_t)ra * N_COLS + l * 4);
        if (rb >= 0) vb = *(const float4*)(X + (size_t)rb * N_COLS + l * 4);
        unsigned int d0 = (unsigned)f2bf(va.x) | ((unsigned)f2bf(vb.x) << 16);
        unsigned int d1 = (unsigned)f2bf(va.y) | ((unsigned)f2bf(vb.y) << 16);
        unsigned int d2 = (unsigned)f2bf(va.z) | ((unsigned)f2bf(vb.z) << 16);
        unsigned int d3 = (unsigned)f2bf(va.w) | ((unsigned)f2bf(vb.w) << 16);
        int c0 = l * 4;
        sT32[(c0 + 0) * 32 + ((p2 + l) & 31)] = d0;   // (c0+j)>>2 == l
        sT32[(c0 + 1) * 32 + ((p2 + l) & 31)] = d1;
        sT32[(c0 + 2) * 32 + ((p2 + l) & 31)] = d2;
        sT32[(c0 + 3) * 32 + ((p2 + l) & 31)] = d3;
    }
    __syncthreads();

    int cb = t >> 3, pc = t & 7;
    #pragma unroll
    for (int j = 0; j < 8; ++j) {
        int col = cb + j * 32;
        int rot = col >> 2;
        const unsigned int* base = &sT32[col * 32];
        uint4 o;
        o.x = base[(pc * 4 + 0 + rot) & 31];
        o.y = base[(pc * 4 + 1 + rot) & 31];
        o.z = base[(pc * 4 + 2 + rot) & 31];
        o.w = base[(pc * 4 + 3 + rot) & 31];
        *(uint4*)(Xst + (size_t)col * XP + p0 + pc * 8) = o;
    }
}

// ---------------- cov via bf16 MFMA syrk ----------------
__global__ __launch_bounds__(256) void cov_mfma(const unsigned short* __restrict__ Xst,
                                                const int* __restrict__ meta,
                                                float* __restrict__ cov) {
    __shared__ unsigned short sA[128][72];
    __shared__ unsigned short sB[128][72];
    int cls = blockIdx.y;
    int tile = blockIdx.x;
    int ti = (tile == 2) ? 1 : 0;
    int tj = (tile == 0) ? 0 : 1;
    int kb = meta[cls];
    int len = meta[cls + 1] - kb;
    int nch = len >> 6;
    int s = blockIdx.z;
    int ch0 = (nch * s) / SPL, ch1 = (nch * (s + 1)) / SPL;
    if (ch0 >= ch1) return;

    int t = threadIdx.x;
    int lane = t & 63, wave = t >> 6;
    int wro = (wave >> 1) * 64, wco = (wave & 1) * 64;

    f32x4 acc[4][4] = {};

    int sr = t >> 1;
    int sq = (t & 1) * 32;

    for (int ch = ch0; ch < ch1; ++ch) {
        int k0 = kb + ch * 64;
        const uint4* ga = (const uint4*)(Xst + (size_t)(ti * 128 + sr) * XP + k0 + sq);
        const uint4* gb = (const uint4*)(Xst + (size_t)(tj * 128 + sr) * XP + k0 + sq);
        uint4 a0 = ga[0], a1 = ga[1], a2 = ga[2], a3 = ga[3];
        uint4 b0 = gb[0], b1 = gb[1], b2 = gb[2], b3 = gb[3];
        __syncthreads();
        *(uint4*)&sA[sr][sq]      = a0;
        *(uint4*)&sA[sr][sq + 8]  = a1;
        *(uint4*)&sA[sr][sq + 16] = a2;
        *(uint4*)&sA[sr][sq + 24] = a3;
        *(uint4*)&sB[sr][sq]      = b0;
        *(uint4*)&sB[sr][sq + 8]  = b1;
        *(uint4*)&sB[sr][sq + 16] = b2;
        *(uint4*)&sB[sr][sq + 24] = b3;
        __syncthreads();
        #pragma unroll
        for (int ks = 0; ks < 64; ks += 32) {
            bf16x8 af[4], bfr[4];
            #pragma unroll
            for (int r = 0; r < 4; ++r)
                af[r] = *(const bf16x8*)&sA[wro + r * 16 + (lane & 15)][ks + (lane >> 4) * 8];
            #pragma unroll
            for (int c2 = 0; c2 < 4; ++c2)
                bfr[c2] = *(const bf16x8*)&sB[wco + c2 * 16 + (lane & 15)][ks + (lane >> 4) * 8];
            #pragma unroll
            for (int r = 0; r < 4; ++r) {
                #pragma unroll
                for (int c2 = 0; c2 < 4; ++c2)
                    acc[r][c2] = __builtin_amdgcn_mfma_f32_16x16x32_bf16(af[r], bfr[c2], acc[r][c2], 0, 0, 0);
            }
        }
    }

    float* cb = cov + (size_t)cls * MSZ;
    int prow = ti * 128 + wro + ((lane >> 4) << 2);
    int pcol = tj * 128 + wco + (lane & 15);
    #pragma unroll
    for (int r = 0; r < 4; ++r) {
        #pragma unroll
        for (int c2 = 0; c2 < 4; ++c2) {
            #pragma unroll
            for (int v = 0; v < 4; ++v)
                atomicAdd(&cb[(size_t)(prow + r * 16 + v) * N_COLS + pcol + c2 * 16], acc[r][c2][v]);
        }
    }
}

// ---------------- cvals: c_b = 1 + scal*tr(cov_b)/256 ----------------
__global__ __launch_bounds__(256) void cvals_kernel(const float* __restrict__ cov,
                                                    const int* __restrict__ meta,
                                                    float* __restrict__ cvals) {
    int b = blockIdx.x, t = threadIdx.x;
    float dsum;
    if (b < NCLASS) dsum = cov[(size_t)b * MSZ + t * 257];
    else {
        dsum = 0.f;
        #pragma unroll
        for (int cl = 0; cl < NCLASS; ++cl) dsum += cov[(size_t)cl * MSZ + t * 257];
    }
    __shared__ float red[256];
    red[t] = dsum;
    __syncthreads();
    for (int s = 128; s > 0; s >>= 1) {
        if (t < s) red[t] += red[t + s];
        __syncthreads();
    }
    if (t == 0) cvals[b] = 1.f + scal_of(b, meta) * red[0] / 256.f;
}

// ---------------- prep: E_b = M_b/c_b - I in bf16; grid (11, 32) ----------------
__global__ __launch_bounds__(256) void prep_kernel(const float* __restrict__ cov,
                                                   const int* __restrict__ meta,
                                                   const float* __restrict__ cvals,
                                                   unsigned short* __restrict__ slab) {
    int b = blockIdx.x;   // matrix 0..10
    int t = threadIdx.x;
    float c = cvals[b];
    float es = scal_of(b, meta) / c;
    float dadd = 1.f / c - 1.f;

    int i  = blockIdx.y * 8 + (t >> 5);   // row
    int cg = (t & 31) * 8;                // col group (8 elems)
    bool mb = (i >> 7) > (cg >> 7);       // cov stores upper 128-blocks; mirror (1,0)
    float v[8];
    if (!mb) {
        size_t off = (size_t)i * N_COLS + cg;
        if (b < NCLASS) {
            float4 a = *(const float4*)(cov + (size_t)b * MSZ + off);
            float4 bq = *(const float4*)(cov + (size_t)b * MSZ + off + 4);
            v[0] = a.x; v[1] = a.y; v[2] = a.z; v[3] = a.w;
            v[4] = bq.x; v[5] = bq.y; v[6] = bq.z; v[7] = bq.w;
        } else {
            #pragma unroll
            for (int jj = 0; jj < 8; ++jj) v[jj] = 0.f;
            #pragma unroll
            for (int cl = 0; cl < NCLASS; ++cl) {
                float4 a = *(const float4*)(cov + (size_t)cl * MSZ + off);
                float4 bq = *(const float4*)(cov + (size_t)cl * MSZ + off + 4);
                v[0] += a.x; v[1] += a.y; v[2] += a.z; v[3] += a.w;
                v[4] += bq.x; v[5] += bq.y; v[6] += bq.z; v[7] += bq.w;
            }
        }
    } else {
        #pragma unroll
        for (int jj = 0; jj < 8; ++jj) {
            size_t off = (size_t)(cg + jj) * N_COLS + i;
            float s;
            if (b < NCLASS) s = cov[(size_t)b * MSZ + off];
            else {
                s = 0.f;
                #pragma unroll
                for (int cl = 0; cl < NCLASS; ++cl) s += cov[(size_t)cl * MSZ + off];
            }
            v[jj] = s;
        }
    }
    unsigned short o[8];
    #pragma unroll
    for (int jj = 0; jj < 8; ++jj)
        o[jj] = f2bf(es * v[jj] + ((cg + jj) == i ? dadd : 0.f));
    uint4 pk;
    pk.x = (unsigned)o[0] | ((unsigned)o[1] << 16);
    pk.y = (unsigned)o[2] | ((unsigned)o[3] << 16);
    pk.z = (unsigned)o[4] | ((unsigned)o[5] << 16);
    pk.w = (unsigned)o[6] | ((unsigned)o[7] << 16);
    *(uint4*)&slab[(size_t)b * MSZ + (size_t)i * N_COLS + cg] = pk;
}

// ---------------- mm_stage: D = A*B for symmetric bf16 256x256 (MFMA) ----------------
__global__ __launch_bounds__(256) void mm_stage(unsigned short* __restrict__ slab,
                                                int ai0, int bi0, int di0,
                                                int ai1, int bi1, int di1) {
    int z = blockIdx.z;
    int ai = z ? ai1 : ai0, bi = z ? bi1 : bi0, di = z ? di1 : di0;
    int m = blockIdx.y;
    int tile = blockIdx.x;
    int ti = tile >> 1, tj = tile & 1;
    const unsigned short* A = slab + ((size_t)ai * 11 + m) * MSZ;
    const unsigned short* B = slab + ((size_t)bi * 11 + m) * MSZ;
    unsigned short* D = slab + ((size_t)di * 11 + m) * MSZ;

    __shared__ unsigned short sA[128][72];
    __shared__ unsigned short sB[128][72];
    int t = threadIdx.x;
    int lane = t & 63, wave = t >> 6;
    int wro = (wave >> 1) * 64, wco = (wave & 1) * 64;

    f32x4 acc[4][4] = {};
    int sr = t >> 1;
    int sq = (t & 1) * 32;

    for (int ch = 0; ch < 4; ++ch) {
        int k0 = ch * 64;
        const uint4* ga = (const uint4*)(A + (size_t)(ti * 128 + sr) * N_COLS + k0 + sq);
        const uint4* gb = (const uint4*)(B + (size_t)(tj * 128 + sr) * N_COLS + k0 + sq);
        uint4 a0 = ga[0], a1 = ga[1], a2 = ga[2], a3 = ga[3];
        uint4 b0 = gb[0], b1 = gb[1], b2 = gb[2], b3 = gb[3];
        __syncthreads();
        *(uint4*)&sA[sr][sq]      = a0;
        *(uint4*)&sA[sr][sq + 8]  = a1;
        *(uint4*)&sA[sr][sq + 16] = a2;
        *(uint4*)&sA[sr][sq + 24] = a3;
        *(uint4*)&sB[sr][sq]      = b0;
        *(uint4*)&sB[sr][sq + 8]  = b1;
        *(uint4*)&sB[sr][sq + 16] = b2;
        *(uint4*)&sB[sr][sq + 24] = b3;
        __syncthreads();
        #pragma unroll
        for (int ks = 0; ks < 64; ks += 32) {
            bf16x8 af[4], bfr[4];
            #pragma unroll
            for (int r = 0; r < 4; ++r)
                af[r] = *(const bf16x8*)&sA[wro + r * 16 + (lane & 15)][ks + (lane >> 4) * 8];
            #pragma unroll
            for (int c2 = 0; c2 < 4; ++c2)
                bfr[c2] = *(const bf16x8*)&sB[wco + c2 * 16 + (lane & 15)][ks + (lane >> 4) * 8];
            #pragma unroll
            for (int r = 0; r < 4; ++r) {
                #pragma unroll
                for (int c2 = 0; c2 < 4; ++c2)
                    acc[r][c2] = __builtin_amdgcn_mfma_f32_16x16x32_bf16(af[r], bfr[c2], acc[r][c2], 0, 0, 0);
            }
        }
    }

    int prow = ti * 128 + wro + ((lane >> 4) << 2);
    int pcol = tj * 128 + wco + (lane & 15);
    #pragma unroll
    for (int r = 0; r < 4; ++r) {
        #pragma unroll
        for (int c2 = 0; c2 < 4; ++c2) {
            #pragma unroll
            for (int v = 0; v < 4; ++v)
                D[(size_t)(prow + r * 16 + v) * N_COLS + pcol + c2 * 16] = f2bf(acc[r][c2][v]);
        }
    }
}

// ---------------- trace: Frobenius pairings -> tr(E^k); grid (11, 8) ----------------
__global__ __launch_bounds__(256) void trace_kernel(const unsigned short* __restrict__ slab,
                                                    float* __restrict__ traces) {
    int m = blockIdx.x, t = threadIdx.x;
    int r  = blockIdx.y * 32 + (t >> 3);   // row
    int cs = (t & 7) * 32;                 // col segment (32 elems)
    const unsigned short* E = slab + (size_t)m * MSZ;
    const unsigned short* G = E + (size_t)11 * MSZ;
    const unsigned short* H = E + (size_t)22 * MSZ;
    const unsigned short* K = E + (size_t)33 * MSZ;
    const unsigned short* P = E + (size_t)44 * MSZ;

    float a0 = 0, a1 = 0, a2 = 0, a3 = 0, a4 = 0, a5 = 0, a6 = 0, a7 = 0, a8 = 0;
    float t1 = (r >= cs && r < cs + 32) ? bf2f(E[(size_t)r * 257]) : 0.f;
    size_t rb = (size_t)r * N_COLS + cs;
    #pragma unroll
    for (int cg = 0; cg < 32; cg += 8) {
        float e[8], g[8], h[8], k[8], p[8];
        unpack8(E + rb + cg, e);
        unpack8(G + rb + cg, g);
        unpack8(H + rb + cg, h);
        unpack8(K + rb + cg, k);
        unpack8(P + rb + cg, p);
        #pragma unroll
        for (int j = 0; j < 8; ++j) {
            a0 = fmaf(e[j], e[j], a0);   // tr2
            a1 = fmaf(e[j], g[j], a1);   // tr3
            a2 = fmaf(g[j], g[j], a2);   // tr4
            a3 = fmaf(g[j], h[j], a3);   // tr5
            a4 = fmaf(h[j], h[j], a4);   // tr6
            a5 = fmaf(h[j], k[j], a5);   // tr7
            a6 = fmaf(k[j], k[j], a6);   // tr8
            a7 = fmaf(h[j], p[j], a7);   // tr9
            a8 = fmaf(k[j], p[j], a8);   // tr10
        }
    }
    float vals[10] = {a0, a1, a2, a3, a4, a5, a6, a7, a8, t1};
    #pragma unroll
    for (int v = 0; v < 10; ++v) {
        float x = vals[v];
        #pragma unroll
        for (int d = 32; d > 0; d >>= 1) x += __shfl_down(x, d, 64);
        if ((t & 63) == 0) atomicAdd(&traces[m * 16 + v], x);
    }
}

// ---------------- finalize ----------------
__global__ void finalize_kernel(const float* __restrict__ traces,
                                const float* __restrict__ cvals,
                                const int* __restrict__ meta,
                                float* __restrict__ out) {
    if (threadIdx.x == 0 && blockIdx.x == 0) {
        float logdet[11];
        for (int m = 0; m < 11; ++m) {
            const float* tr = traces + m * 16;
            logdet[m] = 256.f * __logf(cvals[m])
                      + tr[9]
                      - tr[0] / 2.f + tr[1] / 3.f - tr[2] / 4.f + tr[3] / 5.f
                      - tr[4] / 6.f + tr[5] / 7.f - tr[6] / 8.f + tr[7] / 9.f
                      - tr[8] / 10.f;
        }
        float discrimn = 0.5f * logdet[NCLASS];       // GAM1 == 1 => empi == theo
        float compress = 0.f;
        for (int k = 0; k < NCLASS; ++k) {
            float trp = (float)meta[32 + k] + 1e-8f;
            compress += logdet[k] * trp;
        }
        compress = compress / (float)N_ROWS * 0.5f;
        out[0] = -discrimn + compress;                // GAM2 == 1
        out[1] = discrimn;
        out[2] = compress;
        out[3] = discrimn;
        out[4] = compress;
    }
}

extern "C" void kernel_launch(void* const* d_in, const int* in_sizes, int n_in,
                              void* d_out, int out_size, void* d_ws, size_t ws_size,
                              hipStream_t stream) {
    const float* X = (const float*)d_in[0];
    const int*   Y = (const int*)d_in[1];
    float* out = (float*)d_out;

    char* ws = (char*)d_ws;
    const size_t o_cov   = 0;                        // 10*256*256*4 = 2,621,440
    const size_t o_meta  = 2621440;                  // 64 ints
    const size_t o_blkc  = o_meta + 256;             // 2560 ints
    const size_t o_blkb  = o_blkc + 10240;           // 2560 ints
    const size_t o_order = o_blkb + 10240;           // 65536 ints
    const size_t o_small = o_order + 262144;         // cvals (16 f) + traces (176 f)
    const size_t o_xst   = o_small + 1024;           // 256*XP*2 = 33,882,112

    float*          cov      = (float*)(ws + o_cov);
    int*            meta     = (int*)(ws + o_meta);
    int*            blk_cnt  = (int*)(ws + o_blkc);
    int*            blk_base = (int*)(ws + o_blkb);
    int*            order    = (int*)(ws + o_order);
    float*          cvals    = (float*)(ws + o_small);
    float*          traces   = (float*)(ws + o_small + 64);
    unsigned short* Xst      = (unsigned short*)(ws + o_xst);
    unsigned short* slab     = Xst;                  // E/G/H/K/P overlay Xst after cov

    hipMemsetAsync(cov, 0, (size_t)NCLASS * MSZ * sizeof(float), stream);
    hipMemsetAsync(ws + o_small, 0, 1024, stream);   // zero cvals+traces (atomic targets)
    hipLaunchKernelGGL(blkhist_kernel, dim3(256), dim3(256), 0, stream, Y, blk_cnt);
    hipLaunchKernelGGL(scan_kernel, dim3(1), dim3(1024), 0, stream, blk_cnt, meta, blk_base);
    hipLaunchKernelGGL(order_kernel, dim3(256), dim3(256), 0, stream, Y, blk_base, order);
    hipLaunchKernelGGL(gather_kernel, dim3(XP / 64), dim3(256), 0, stream, X, order, meta, Xst);
    hipLaunchKernelGGL(cov_mfma, dim3(3, NCLASS, SPL), dim3(256), 0, stream, Xst, meta, cov);
    hipLaunchKernelGGL(cvals_kernel, dim3(11), dim3(256), 0, stream, cov, meta, cvals);
    hipLaunchKernelGGL(prep_kernel, dim3(11, 32), dim3(256), 0, stream, cov, meta, cvals, slab);
    // S1: G = E*E
    hipLaunchKernelGGL(mm_stage, dim3(4, 11, 1), dim3(256), 0, stream, slab, 0, 0, 1, 0, 0, 1);
    // S2: H = E*G ; K = G*G
    hipLaunchKernelGGL(mm_stage, dim3(4, 11, 2), dim3(256), 0, stream, slab, 0, 1, 2, 1, 1, 3);
    // S3: P = H*H
    hipLaunchKernelGGL(mm_stage, dim3(4, 11, 1), dim3(256), 0, stream, slab, 2, 2, 4, 2, 2, 4);
    hipLaunchKernelGGL(trace_kernel, dim3(11, 8), dim3(256), 0, stream, slab, traces);
    hipLaunchKernelGGL(finalize_kernel, dim3(1), dim3(64), 0, stream, traces, cvals, meta, out);
}